// Round 1
// baseline (1066.116 us; speedup 1.0000x reference)
//
#include <hip/hip_runtime.h>
#include <stdint.h>

// ---------------------------------------------------------------------------
// DAGNN: GRU(128->64, T=8) -> GATConv(64->4x64, concat) -> GATConv(256->64)
//        -> segment-mean pool -> FC(64->10) -> log_softmax
// Strategy: bf16 MFMA for all GEMM-shaped work, CSR (counting sort) for the
// edge softmax/aggregation, deterministic pooling via sorted-batch boundaries.
// ---------------------------------------------------------------------------

typedef __attribute__((ext_vector_type(8))) short short8;
typedef __attribute__((ext_vector_type(4))) float f32x4;
typedef __attribute__((ext_vector_type(4))) unsigned short us4;

__device__ __forceinline__ unsigned short f2bf(float f) {
    unsigned u = __float_as_uint(f);
    u += 0x7FFFu + ((u >> 16) & 1u);   // RNE
    return (unsigned short)(u >> 16);
}
__device__ __forceinline__ float bf2f(unsigned short h) {
    return __uint_as_float(((unsigned)h) << 16);
}
__device__ __forceinline__ float lrelu(float x) { return x > 0.f ? x : 0.2f * x; }

// ---------------------------------------------------------------------------
// Pack a weight matrix into MFMA B-fragment order:
// frag f = ct*KT + kt ; element [f][lane][i] = B[k][col],
//   col = ct*16 + (lane&15), k = kt*32 + (lane>>4)*8 + i
// transposed=1: B[k][col] = src[col*ldsrc + k]  (GRU weights, [3H][D] layout)
// transposed=0: B[k][col] = src[k*ldsrc + col]  (W1/W2, [K][NCOL] layout)
// ---------------------------------------------------------------------------
__global__ void k_pack(const float* __restrict__ src, unsigned short* __restrict__ dst,
                       int K, int NCOL, int ldsrc, int transposed) {
    int id = blockIdx.x * blockDim.x + threadIdx.x;
    int KT = K >> 5;
    int nfrag = (NCOL >> 4) * KT;
    if (id >= nfrag * 64) return;
    int l = id & 63;
    int f = id >> 6;
    int kt = f % KT, ct = f / KT;
    int col = ct * 16 + (l & 15);
    int kbase = kt * 32 + ((l >> 4) << 3);
#pragma unroll
    for (int i = 0; i < 8; i++) {
        int k = kbase + i;
        float v = transposed ? src[(size_t)col * ldsrc + k] : src[(size_t)k * ldsrc + col];
        dst[((size_t)f * 64 + l) * 8 + i] = f2bf(v);
    }
}

// ---------------------------------------------------------------------------
// Fused GRU. Block = 64 nodes, 256 threads (4 waves). Wave w owns hidden
// columns j in [16w,16w+16) of each gate (r,z,n): gi tiles ct = g*4+w.
// x staged per step into LDS in A-fragment order; h kept in D-layout regs.
// ---------------------------------------------------------------------------
__launch_bounds__(256, 2)
__global__ void k_gru(const float* __restrict__ x,
                      const unsigned short* __restrict__ pgi,
                      const unsigned short* __restrict__ pgh,
                      const float* __restrict__ b_ih, const float* __restrict__ b_hh,
                      unsigned short* __restrict__ h1, int N) {
    __shared__ unsigned short x_pack[4 * 4 * 64 * 8];  // [m][kt][lane][8]
    __shared__ unsigned short h_pack[4 * 2 * 64 * 8];

    const int tid = threadIdx.x;
    const int w = tid >> 6;
    const int l = tid & 63;
    const int row0 = blockIdx.x * 64;

    short8 wgi[3][4], wgh[3][2];
#pragma unroll
    for (int g = 0; g < 3; g++) {
        int ctg = g * 4 + w;
#pragma unroll
        for (int kt = 0; kt < 4; kt++)
            wgi[g][kt] = *(const short8*)(pgi + ((size_t)(ctg * 4 + kt) * 64 + l) * 8);
#pragma unroll
        for (int kt = 0; kt < 2; kt++)
            wgh[g][kt] = *(const short8*)(pgh + ((size_t)(ctg * 2 + kt) * 64 + l) * 8);
    }
    const int j = (w << 4) + (l & 15);  // hidden index this lane owns
    const float bi_r = b_ih[j], bi_z = b_ih[64 + j], bi_n = b_ih[128 + j];
    const float bh_r = b_hh[j], bh_z = b_hh[64 + j], bh_n = b_hh[128 + j];

    f32x4 hreg[4];
    const f32x4 z4 = {0.f, 0.f, 0.f, 0.f};
#pragma unroll
    for (int m = 0; m < 4; m++) hreg[m] = z4;

    const int sr = tid >> 2, sub = tid & 3;
    const int snode = min(row0 + sr, N - 1);
    const int slane = (sr & 15) | (sub << 4);
    const int sm = sr >> 4;
    const float* xbase = x + (size_t)snode * 1024;

    for (int t = 0; t < 8; t++) {
        __syncthreads();
        // stage x[:,t,:] -> A-fragment order (bf16)
        const float* xp = xbase + t * 128;
#pragma unroll
        for (int it = 0; it < 4; it++) {
            int d0 = it * 32 + sub * 8;
            float4 va = *(const float4*)(xp + d0);
            float4 vb = *(const float4*)(xp + d0 + 4);
            short8 pk;
            pk[0] = (short)f2bf(va.x); pk[1] = (short)f2bf(va.y);
            pk[2] = (short)f2bf(va.z); pk[3] = (short)f2bf(va.w);
            pk[4] = (short)f2bf(vb.x); pk[5] = (short)f2bf(vb.y);
            pk[6] = (short)f2bf(vb.z); pk[7] = (short)f2bf(vb.w);
            *(short8*)&x_pack[((sm * 4 + it) * 64 + slane) * 8] = pk;
        }
        __syncthreads();

        f32x4 agi[4][3], agh[4][3];
#pragma unroll
        for (int m = 0; m < 4; m++)
#pragma unroll
            for (int g = 0; g < 3; g++) { agi[m][g] = z4; agh[m][g] = z4; }

#pragma unroll
        for (int m = 0; m < 4; m++) {
#pragma unroll
            for (int kt = 0; kt < 4; kt++) {
                short8 a = *(const short8*)&x_pack[((m * 4 + kt) * 64 + l) * 8];
#pragma unroll
                for (int g = 0; g < 3; g++)
                    agi[m][g] = __builtin_amdgcn_mfma_f32_16x16x32_bf16(a, wgi[g][kt], agi[m][g], 0, 0, 0);
            }
            if (t > 0) {
#pragma unroll
                for (int kt = 0; kt < 2; kt++) {
                    short8 a = *(const short8*)&h_pack[((m * 2 + kt) * 64 + l) * 8];
#pragma unroll
                    for (int g = 0; g < 3; g++)
                        agh[m][g] = __builtin_amdgcn_mfma_f32_16x16x32_bf16(a, wgh[g][kt], agh[m][g], 0, 0, 0);
                }
            }
        }
        // gates (h0 = 0 handled by agh=0 at t==0: gh = b_hh, matches reference)
#pragma unroll
        for (int m = 0; m < 4; m++) {
#pragma unroll
            for (int q = 0; q < 4; q++) {
                float ir = agi[m][0][q] + bi_r;
                float iz = agi[m][1][q] + bi_z;
                float in_ = agi[m][2][q] + bi_n;
                float hr = agh[m][0][q] + bh_r;
                float hz = agh[m][1][q] + bh_z;
                float hn = agh[m][2][q] + bh_n;
                float rr = 1.f / (1.f + __expf(-(ir + hr)));
                float zz = 1.f / (1.f + __expf(-(iz + hz)));
                float nn = tanhf(in_ + rr * hn);
                hreg[m][q] = (1.f - zz) * nn + zz * hreg[m][q];
            }
        }
        __syncthreads();  // everyone done reading h_pack before overwrite
        // scatter h (D-layout) -> h_pack (A-fragment layout) for next step
#pragma unroll
        for (int m = 0; m < 4; m++) {
#pragma unroll
            for (int q = 0; q < 4; q++) {
                int rl = ((l >> 4) << 2) + q;                 // row within 16-tile
                int lane2 = rl | (((j >> 3) & 3) << 4);
                h_pack[((m * 2 + (j >> 5)) * 64 + lane2) * 8 + (j & 7)] = f2bf(hreg[m][q]);
            }
        }
    }
    // final h -> global bf16 [N][64]
#pragma unroll
    for (int m = 0; m < 4; m++) {
#pragma unroll
        for (int q = 0; q < 4; q++) {
            int node = row0 + (m << 4) + ((l >> 4) << 2) + q;
            if (node < N) h1[(size_t)node * 64 + j] = f2bf(hreg[m][q]);
        }
    }
}

// ---------------------------------------------------------------------------
// Generic row-tile GEMM: C[N][NCOL] = A[N][K] (bf16) x packB (B-fragments)
// Block = 64 rows, 4 waves; wave w owns cols [w*NCOL/4, (w+1)*NCOL/4)
// ---------------------------------------------------------------------------
template <int K, int NCOL>
__launch_bounds__(256, 2)
__global__ void k_gemm(const unsigned short* __restrict__ A,
                       const unsigned short* __restrict__ packB,
                       unsigned short* __restrict__ C, int N) {
    constexpr int KT = K >> 5;
    constexpr int CPW = NCOL >> 6;  // 16-col tiles per wave
    __shared__ unsigned short a_pack[4 * KT * 64 * 8];

    const int tid = threadIdx.x;
    const int w = tid >> 6;
    const int l = tid & 63;
    const int row0 = blockIdx.x * 64;

    short8 bf[CPW][KT];
#pragma unroll
    for (int ci = 0; ci < CPW; ci++)
#pragma unroll
        for (int kt = 0; kt < KT; kt++)
            bf[ci][kt] = *(const short8*)(packB + ((size_t)((w * CPW + ci) * KT + kt) * 64 + l) * 8);

    const int sr = tid >> 2, sub = tid & 3;
    const int snode = min(row0 + sr, N - 1);
    const unsigned short* ap = A + (size_t)snode * K;
#pragma unroll
    for (int it = 0; it < KT; it++) {
        int d0 = it * 32 + sub * 8;
        short8 v = *(const short8*)(ap + d0);
        *(short8*)&a_pack[(((sr >> 4) * KT + it) * 64 + ((sr & 15) | (sub << 4))) * 8] = v;
    }
    __syncthreads();

    const f32x4 z4 = {0.f, 0.f, 0.f, 0.f};
    f32x4 acc[4][CPW];
#pragma unroll
    for (int m = 0; m < 4; m++)
#pragma unroll
        for (int ci = 0; ci < CPW; ci++) acc[m][ci] = z4;

#pragma unroll
    for (int m = 0; m < 4; m++)
#pragma unroll
        for (int kt = 0; kt < KT; kt++) {
            short8 a = *(const short8*)&a_pack[((m * KT + kt) * 64 + l) * 8];
#pragma unroll
            for (int ci = 0; ci < CPW; ci++)
                acc[m][ci] = __builtin_amdgcn_mfma_f32_16x16x32_bf16(a, bf[ci][kt], acc[m][ci], 0, 0, 0);
        }

#pragma unroll
    for (int m = 0; m < 4; m++)
#pragma unroll
        for (int ci = 0; ci < CPW; ci++)
#pragma unroll
            for (int q = 0; q < 4; q++) {
                int node = row0 + (m << 4) + ((l >> 4) << 2) + q;
                int col = w * (NCOL / 4) + ci * 16 + (l & 15);
                if (node < N) C[(size_t)node * NCOL + col] = f2bf(acc[m][ci][q]);
            }
}

// ---------------------------------------------------------------------------
// Per-node attention logits: a_s[n,h] = sum_c xs[n,h,c]*att_src[h,c] etc.
// One wave per node, lane = channel.
// ---------------------------------------------------------------------------
template <int H>
__global__ void k_att(const unsigned short* __restrict__ xs,
                      const float* __restrict__ att_src, const float* __restrict__ att_dst,
                      float* __restrict__ oa_s, float* __restrict__ oa_d, int N) {
    int v = blockIdx.x * 4 + (threadIdx.x >> 6);
    if (v >= N) return;
    int l = threadIdx.x & 63;
#pragma unroll
    for (int h = 0; h < H; h++) {
        float val = bf2f(xs[(size_t)v * (H * 64) + h * 64 + l]);
        float s = val * att_src[h * 64 + l];
        float d = val * att_dst[h * 64 + l];
#pragma unroll
        for (int m = 32; m; m >>= 1) { s += __shfl_xor(s, m); d += __shfl_xor(d, m); }
        if (l == 0) { oa_s[v * H + h] = s; oa_d[v * H + h] = d; }
    }
}

// --------------------------- CSR build -------------------------------------
__global__ void k_deg(const int* __restrict__ dst, int* __restrict__ deg, int E) {
    int i = blockIdx.x * blockDim.x + threadIdx.x;
    if (i < E) atomicAdd(&deg[dst[i]], 1);
}
__global__ void k_scan(const int* __restrict__ deg, int* __restrict__ off, int N) {
    __shared__ int sb[1024];
    __shared__ int carry;
    int tid = threadIdx.x;
    if (tid == 0) { carry = 0; off[0] = 0; }
    __syncthreads();
    for (int base = 0; base < N; base += 1024) {
        int i = base + tid;
        sb[tid] = (i < N) ? deg[i] : 0;
        __syncthreads();
        for (int s = 1; s < 1024; s <<= 1) {
            int t = (tid >= s) ? sb[tid - s] : 0;
            __syncthreads();
            sb[tid] += t;
            __syncthreads();
        }
        if (i < N) off[i + 1] = carry + sb[tid];
        __syncthreads();
        if (tid == 1023) carry += sb[1023];
        __syncthreads();
    }
}
__global__ void k_fill(const int* __restrict__ srcv, const int* __restrict__ dstv,
                       const int* __restrict__ off, int* __restrict__ cursor,
                       int* __restrict__ ssrc, int E) {
    int i = blockIdx.x * blockDim.x + threadIdx.x;
    if (i < E) {
        int d = dstv[i];
        int pos = off[d] + atomicAdd(&cursor[d], 1);
        ssrc[pos] = srcv[i];
    }
}

// ---------------------------------------------------------------------------
// GAT layer-1 aggregation (H=4, C=64). Wave per dst node; lane l covers
// channels [4l,4l+4); head = l>>4. Online softmax; self-loop first.
// ---------------------------------------------------------------------------
__global__ void k_agg1(const unsigned short* __restrict__ xs,
                       const float* __restrict__ a_s, const float* __restrict__ a_d,
                       const int* __restrict__ off, const int* __restrict__ ssrc,
                       const float* __restrict__ bias,
                       unsigned short* __restrict__ out, int N) {
    int v = blockIdx.x * 4 + (threadIdx.x >> 6);
    if (v >= N) return;
    int l = threadIdx.x & 63;
    int h = l >> 4;
    int c0 = l * 4;
    float adv = a_d[v * 4 + h];
    float e = lrelu(a_s[v * 4 + h] + adv);
    float m = e, s = 1.0f;
    us4 xv = *(const us4*)(xs + (size_t)v * 256 + c0);
    float a0 = bf2f(xv[0]), a1 = bf2f(xv[1]), a2 = bf2f(xv[2]), a3 = bf2f(xv[3]);
    int beg = off[v], end = off[v + 1];
    for (int idx = beg; idx < end; idx++) {
        int u = ssrc[idx];
        float eu = lrelu(a_s[u * 4 + h] + adv);
        float mn = fmaxf(m, eu);
        float cm = __expf(m - mn), ce = __expf(eu - mn);
        s = s * cm + ce;
        us4 xu = *(const us4*)(xs + (size_t)u * 256 + c0);
        a0 = a0 * cm + ce * bf2f(xu[0]);
        a1 = a1 * cm + ce * bf2f(xu[1]);
        a2 = a2 * cm + ce * bf2f(xu[2]);
        a3 = a3 * cm + ce * bf2f(xu[3]);
        m = mn;
    }
    float inv = 1.0f / (s + 1e-16f);
    us4 ov;
    ov[0] = f2bf(fmaxf(a0 * inv + bias[c0 + 0], 0.f));
    ov[1] = f2bf(fmaxf(a1 * inv + bias[c0 + 1], 0.f));
    ov[2] = f2bf(fmaxf(a2 * inv + bias[c0 + 2], 0.f));
    ov[3] = f2bf(fmaxf(a3 * inv + bias[c0 + 3], 0.f));
    *(us4*)(out + (size_t)v * 256 + c0) = ov;
}

// GAT layer-2 aggregation (H=1, C=64). Wave per node; lane = channel.
__global__ void k_agg2(const unsigned short* __restrict__ xs,
                       const float* __restrict__ a_s, const float* __restrict__ a_d,
                       const int* __restrict__ off, const int* __restrict__ ssrc,
                       const float* __restrict__ bias,
                       float* __restrict__ out, int N) {
    int v = blockIdx.x * 4 + (threadIdx.x >> 6);
    if (v >= N) return;
    int l = threadIdx.x & 63;
    float adv = a_d[v];
    float e = lrelu(a_s[v] + adv);
    float m = e, s = 1.0f;
    float acc = bf2f(xs[(size_t)v * 64 + l]);
    int beg = off[v], end = off[v + 1];
    for (int idx = beg; idx < end; idx++) {
        int u = ssrc[idx];
        float eu = lrelu(a_s[u] + adv);
        float mn = fmaxf(m, eu);
        float cm = __expf(m - mn), ce = __expf(eu - mn);
        s = s * cm + ce;
        acc = acc * cm + ce * bf2f(xs[(size_t)u * 64 + l]);
        m = mn;
    }
    float o = acc / (s + 1e-16f) + bias[l];
    out[(size_t)v * 64 + l] = fmaxf(o, 0.f);
}

// --------------------------- pooling + FC ----------------------------------
__global__ void k_bounds(const int* __restrict__ batch, int* __restrict__ start, int N, int G) {
    int g = blockIdx.x * blockDim.x + threadIdx.x;
    if (g > G) return;
    int lo = 0, hi = N;
    while (lo < hi) {
        int mid = (lo + hi) >> 1;
        if (batch[mid] < g) lo = mid + 1; else hi = mid;
    }
    start[g] = lo;
}
__global__ void k_pool(const float* __restrict__ h3, const int* __restrict__ start,
                       const float* __restrict__ fc_w, const float* __restrict__ fc_b,
                       float* __restrict__ out, int G) {
    __shared__ float red[4][64];
    __shared__ float meanv[64];
    __shared__ float lg[10];
    int g = blockIdx.x;
    int tid = threadIdx.x, c = tid & 63, ro = tid >> 6;
    int s0 = start[g], s1 = start[g + 1];
    float p = 0.f;
    for (int r = s0 + ro; r < s1; r += 4) p += h3[(size_t)r * 64 + c];
    red[ro][c] = p;
    __syncthreads();
    if (tid < 64) {
        float tot = red[0][c] + red[1][c] + red[2][c] + red[3][c];
        float cnt = (float)max(s1 - s0, 1);
        meanv[c] = tot / cnt;
    }
    __syncthreads();
    if (tid < 10) {
        float lv = fc_b[tid];
        for (int k = 0; k < 64; k++) lv += meanv[k] * fc_w[k * 10 + tid];
        lg[tid] = lv;
    }
    __syncthreads();
    if (tid == 0) {
        float mx = lg[0];
        for (int k = 1; k < 10; k++) mx = fmaxf(mx, lg[k]);
        float ss = 0.f;
        for (int k = 0; k < 10; k++) ss += expf(lg[k] - mx);
        float lse = mx + logf(ss);
        for (int k = 0; k < 10; k++) out[g * 10 + k] = lg[k] - lse;
    }
}

// ---------------------------------------------------------------------------
extern "C" void kernel_launch(void* const* d_in, const int* in_sizes, int n_in,
                              void* d_out, int out_size, void* d_ws, size_t ws_size,
                              hipStream_t stream) {
    const float* x = (const float*)d_in[0];
    const int* ei = (const int*)d_in[1];
    const int* batch = (const int*)d_in[2];
    const float* w_ih = (const float*)d_in[4];
    const float* w_hh = (const float*)d_in[5];
    const float* b_ih = (const float*)d_in[6];
    const float* b_hh = (const float*)d_in[7];
    const float* W1 = (const float*)d_in[8];
    const float* as1 = (const float*)d_in[9];
    const float* ad1 = (const float*)d_in[10];
    const float* b1 = (const float*)d_in[11];
    const float* W2 = (const float*)d_in[12];
    const float* as2 = (const float*)d_in[13];
    const float* ad2 = (const float*)d_in[14];
    const float* b2 = (const float*)d_in[15];
    const float* fc_w = (const float*)d_in[18];
    const float* fc_b = (const float*)d_in[19];
    float* out = (float*)d_out;

    const int N = in_sizes[0] / (8 * 128);   // 100000
    const int E = in_sizes[1] / 2;           // 1600000
    const int G = 128;                        // num_graphs (reference constant)

    char* ws = (char*)d_ws;
    size_t cur = 0;
    auto alloc = [&](size_t b) { size_t r = cur; cur += (b + 255) & ~(size_t)255; return r; };
    unsigned short* p_gi = (unsigned short*)(ws + alloc((size_t)12 * 4 * 64 * 8 * 2));
    unsigned short* p_gh = (unsigned short*)(ws + alloc((size_t)12 * 2 * 64 * 8 * 2));
    unsigned short* p_w1 = (unsigned short*)(ws + alloc((size_t)16 * 2 * 64 * 8 * 2));
    unsigned short* p_w2 = (unsigned short*)(ws + alloc((size_t)4 * 8 * 64 * 8 * 2));
    unsigned short* h1 = (unsigned short*)(ws + alloc((size_t)N * 64 * 2));
    unsigned short* xs1 = (unsigned short*)(ws + alloc((size_t)N * 256 * 2));  // reused as xs2
    unsigned short* h2 = (unsigned short*)(ws + alloc((size_t)N * 256 * 2));
    float* h3 = (float*)(ws + alloc((size_t)N * 64 * 4));
    float* aS = (float*)(ws + alloc((size_t)N * 4 * 4));
    float* aD = (float*)(ws + alloc((size_t)N * 4 * 4));
    int* deg = (int*)(ws + alloc((size_t)N * 4));  // reused as cursor
    int* offp = (int*)(ws + alloc((size_t)(N + 1) * 4));
    int* ssrc = (int*)(ws + alloc((size_t)E * 4));
    int* startb = (int*)(ws + alloc((size_t)(G + 1) * 4));
    // total ~152 MB

    // ---- weight packing ----
    k_pack<<<12, 256, 0, stream>>>(w_ih, p_gi, 128, 192, 128, 1);
    k_pack<<<6, 256, 0, stream>>>(w_hh, p_gh, 64, 192, 64, 1);
    k_pack<<<8, 256, 0, stream>>>(W1, p_w1, 64, 256, 256, 0);
    k_pack<<<8, 256, 0, stream>>>(W2, p_w2, 256, 64, 64, 0);

    // ---- CSR by dst (self-loops handled analytically in agg kernels) ----
    hipMemsetAsync(deg, 0, (size_t)N * 4, stream);
    k_deg<<<(E + 255) / 256, 256, 0, stream>>>(ei + E, deg, E);
    k_scan<<<1, 1024, 0, stream>>>(deg, offp, N);
    hipMemsetAsync(deg, 0, (size_t)N * 4, stream);  // reuse as cursor
    k_fill<<<(E + 255) / 256, 256, 0, stream>>>(ei, ei + E, offp, deg, ssrc, E);

    const int nb64 = (N + 63) / 64;   // 1563
    const int nb4 = (N + 3) / 4;      // 25000

    // ---- GRU ----
    k_gru<<<nb64, 256, 0, stream>>>(x, p_gi, p_gh, b_ih, b_hh, h1, N);

    // ---- GAT layer 1 ----
    k_gemm<64, 256><<<nb64, 256, 0, stream>>>(h1, p_w1, xs1, N);
    k_att<4><<<nb4, 256, 0, stream>>>(xs1, as1, ad1, aS, aD, N);
    k_agg1<<<nb4, 256, 0, stream>>>(xs1, aS, aD, offp, ssrc, b1, h2, N);

    // ---- GAT layer 2 ----
    k_gemm<256, 64><<<nb64, 256, 0, stream>>>(h2, p_w2, xs1 /*xs2*/, N);
    k_att<1><<<nb4, 256, 0, stream>>>(xs1, as2, ad2, aS, aD, N);
    k_agg2<<<nb4, 256, 0, stream>>>(xs1, aS, aD, offp, ssrc, b2, h3, N);

    // ---- pooling + FC + log_softmax (aw == 1 exactly; attn_w/b unused) ----
    k_bounds<<<1, 256, 0, stream>>>(batch, startb, N, G);
    k_pool<<<G, 256, 0, stream>>>(h3, startb, fc_w, fc_b, out, G);
}

// Round 2
// 747.214 us; speedup vs baseline: 1.4268x; 1.4268x over previous
//
#include <hip/hip_runtime.h>
#include <stdint.h>

// ---------------------------------------------------------------------------
// DAGNN: GRU(128->64, T=8) -> GATConv(64->4x64, concat) -> GATConv(256->64)
//        -> segment-mean pool -> FC(64->10) -> log_softmax
// R2: pipelined GRU + fast transcendentals, hierarchical scan, att fused into
// GEMM epilogues, prefetched aggregation loops.
// ---------------------------------------------------------------------------

typedef __attribute__((ext_vector_type(8))) short short8;
typedef __attribute__((ext_vector_type(4))) float f32x4;
typedef __attribute__((ext_vector_type(4))) unsigned short us4;

__device__ __forceinline__ unsigned short f2bf(float f) {
    unsigned u = __float_as_uint(f);
    u += 0x7FFFu + ((u >> 16) & 1u);   // RNE
    return (unsigned short)(u >> 16);
}
__device__ __forceinline__ float bf2f(unsigned short h) {
    return __uint_as_float(((unsigned)h) << 16);
}
__device__ __forceinline__ float lrelu(float x) { return x > 0.f ? x : 0.2f * x; }
__device__ __forceinline__ float fsig(float a) {           // sigmoid, ~7 VALU
    return __builtin_amdgcn_rcpf(1.f + __expf(-a));
}
__device__ __forceinline__ float ftanh(float a) {          // tanh via exp+rcp
    return 2.f * __builtin_amdgcn_rcpf(1.f + __expf(-2.f * a)) - 1.f;
}

// ---------------------------------------------------------------------------
// Pack a weight matrix into MFMA B-fragment order:
// frag f = ct*KT + kt ; element [f][lane][i] = B[k][col],
//   col = ct*16 + (lane&15), k = kt*32 + (lane>>4)*8 + i
// ---------------------------------------------------------------------------
__global__ void k_pack(const float* __restrict__ src, unsigned short* __restrict__ dst,
                       int K, int NCOL, int ldsrc, int transposed) {
    int id = blockIdx.x * blockDim.x + threadIdx.x;
    int KT = K >> 5;
    int nfrag = (NCOL >> 4) * KT;
    if (id >= nfrag * 64) return;
    int l = id & 63;
    int f = id >> 6;
    int kt = f % KT, ct = f / KT;
    int col = ct * 16 + (l & 15);
    int kbase = kt * 32 + ((l >> 4) << 3);
#pragma unroll
    for (int i = 0; i < 8; i++) {
        int k = kbase + i;
        float v = transposed ? src[(size_t)col * ldsrc + k] : src[(size_t)k * ldsrc + col];
        dst[((size_t)f * 64 + l) * 8 + i] = f2bf(v);
    }
}

// ---------------------------------------------------------------------------
// Fused GRU. Block = 64 nodes, 256 threads (4 waves). Wave w owns hidden
// columns j in [16w,16w+16). x prefetched 1 step ahead; gh_r/gh_z accumulate
// into the same MFMA accs as gi_r/gi_z (gates only need the sums).
// ---------------------------------------------------------------------------
__launch_bounds__(256, 2)
__global__ void k_gru(const float* __restrict__ x,
                      const unsigned short* __restrict__ pgi,
                      const unsigned short* __restrict__ pgh,
                      const float* __restrict__ b_ih, const float* __restrict__ b_hh,
                      unsigned short* __restrict__ h1, int N) {
    __shared__ unsigned short x_pack[4 * 4 * 64 * 8];  // 8 KB
    __shared__ unsigned short h_pack[4 * 2 * 64 * 8];  // 4 KB

    const int tid = threadIdx.x;
    const int w = tid >> 6;
    const int l = tid & 63;
    const int row0 = blockIdx.x * 64;

    short8 wgi[3][4], wgh[3][2];
#pragma unroll
    for (int g = 0; g < 3; g++) {
        int ctg = g * 4 + w;
#pragma unroll
        for (int kt = 0; kt < 4; kt++)
            wgi[g][kt] = *(const short8*)(pgi + ((size_t)(ctg * 4 + kt) * 64 + l) * 8);
#pragma unroll
        for (int kt = 0; kt < 2; kt++)
            wgh[g][kt] = *(const short8*)(pgh + ((size_t)(ctg * 2 + kt) * 64 + l) * 8);
    }
    const int j = (w << 4) + (l & 15);  // hidden index this lane owns
    const float bs_r = b_ih[j] + b_hh[j];
    const float bs_z = b_ih[64 + j] + b_hh[64 + j];
    const float bi_n = b_ih[128 + j], bh_n = b_hh[128 + j];

    f32x4 hreg[4];
    const f32x4 z4 = {0.f, 0.f, 0.f, 0.f};
#pragma unroll
    for (int m = 0; m < 4; m++) hreg[m] = z4;

    const int sr = tid >> 2, sub = tid & 3;
    const int snode = min(row0 + sr, N - 1);
    const int slane = (sr & 15) | (sub << 4);
    const int sm = sr >> 4;
    const float* xbase = x + (size_t)snode * 1024;

    // prologue: prefetch t=0
    float4 pre[8];
#pragma unroll
    for (int it = 0; it < 4; it++) {
        int d0 = it * 32 + sub * 8;
        pre[2 * it] = *(const float4*)(xbase + d0);
        pre[2 * it + 1] = *(const float4*)(xbase + d0 + 4);
    }

    for (int t = 0; t < 8; t++) {
        // convert prefetched x_t (vmcnt wait lands here)
        short8 pk[4];
#pragma unroll
        for (int it = 0; it < 4; it++) {
            float4 va = pre[2 * it], vb = pre[2 * it + 1];
            short8 p;
            p[0] = (short)f2bf(va.x); p[1] = (short)f2bf(va.y);
            p[2] = (short)f2bf(va.z); p[3] = (short)f2bf(va.w);
            p[4] = (short)f2bf(vb.x); p[5] = (short)f2bf(vb.y);
            p[6] = (short)f2bf(vb.z); p[7] = (short)f2bf(vb.w);
            pk[it] = p;
        }
        // write phase: h_{t-1} scatter + x_t stage (prev readers done at loop-end barrier)
        if (t > 0) {
#pragma unroll
            for (int m = 0; m < 4; m++)
#pragma unroll
                for (int q = 0; q < 4; q++) {
                    int rl = ((l >> 4) << 2) + q;
                    int lane2 = rl | (((j >> 3) & 3) << 4);
                    h_pack[((m * 2 + (j >> 5)) * 64 + lane2) * 8 + (j & 7)] = f2bf(hreg[m][q]);
                }
        }
#pragma unroll
        for (int it = 0; it < 4; it++)
            *(short8*)&x_pack[((sm * 4 + it) * 64 + slane) * 8] = pk[it];
        __syncthreads();

        // issue t+1 loads — land during MFMA+gates
        if (t < 7) {
            const float* xp = xbase + (t + 1) * 128;
#pragma unroll
            for (int it = 0; it < 4; it++) {
                int d0 = it * 32 + sub * 8;
                pre[2 * it] = *(const float4*)(xp + d0);
                pre[2 * it + 1] = *(const float4*)(xp + d0 + 4);
            }
        }

        f32x4 agi[4][3], aghn[4];
#pragma unroll
        for (int m = 0; m < 4; m++) {
            agi[m][0] = z4; agi[m][1] = z4; agi[m][2] = z4; aghn[m] = z4;
        }

#pragma unroll
        for (int m = 0; m < 4; m++) {
#pragma unroll
            for (int kt = 0; kt < 4; kt++) {
                short8 a = *(const short8*)&x_pack[((m * 4 + kt) * 64 + l) * 8];
#pragma unroll
                for (int g = 0; g < 3; g++)
                    agi[m][g] = __builtin_amdgcn_mfma_f32_16x16x32_bf16(a, wgi[g][kt], agi[m][g], 0, 0, 0);
            }
            if (t > 0) {
#pragma unroll
                for (int kt = 0; kt < 2; kt++) {
                    short8 a = *(const short8*)&h_pack[((m * 2 + kt) * 64 + l) * 8];
                    agi[m][0] = __builtin_amdgcn_mfma_f32_16x16x32_bf16(a, wgh[0][kt], agi[m][0], 0, 0, 0);
                    agi[m][1] = __builtin_amdgcn_mfma_f32_16x16x32_bf16(a, wgh[1][kt], agi[m][1], 0, 0, 0);
                    aghn[m]   = __builtin_amdgcn_mfma_f32_16x16x32_bf16(a, wgh[2][kt], aghn[m], 0, 0, 0);
                }
            }
        }
        // gates: r/z use summed accs + folded biases; n needs r*(gh_n + bh_n)
#pragma unroll
        for (int m = 0; m < 4; m++) {
#pragma unroll
            for (int q = 0; q < 4; q++) {
                float rr = fsig(agi[m][0][q] + bs_r);
                float zz = fsig(agi[m][1][q] + bs_z);
                float hn = aghn[m][q] + bh_n;
                float nn = ftanh(agi[m][2][q] + bi_n + rr * hn);
                hreg[m][q] = nn + zz * (hreg[m][q] - nn);
            }
        }
        __syncthreads();  // readers done before next write phase
    }
#pragma unroll
    for (int m = 0; m < 4; m++)
#pragma unroll
        for (int q = 0; q < 4; q++) {
            int node = row0 + (m << 4) + ((l >> 4) << 2) + q;
            if (node < N) h1[(size_t)node * 64 + j] = f2bf(hreg[m][q]);
        }
}

// ---------------------------------------------------------------------------
// GEMM1: xs1[N][256] = h1[N][64] x W1 (+ fused per-head attention logits)
// Block = 64 rows, 4 waves; wave w owns cols [64w,64w+64) == head w.
// ---------------------------------------------------------------------------
__launch_bounds__(256, 2)
__global__ void k_gemm1(const unsigned short* __restrict__ A,
                        const unsigned short* __restrict__ packB,
                        const float* __restrict__ att_s, const float* __restrict__ att_d,
                        unsigned short* __restrict__ C,
                        float* __restrict__ aS, float* __restrict__ aD, int N) {
    constexpr int KT = 2, CPW = 4;
    __shared__ unsigned short a_pack[4 * KT * 64 * 8];

    const int tid = threadIdx.x, w = tid >> 6, l = tid & 63;
    const int row0 = blockIdx.x * 64;

    short8 bf[CPW][KT];
#pragma unroll
    for (int ci = 0; ci < CPW; ci++)
#pragma unroll
        for (int kt = 0; kt < KT; kt++)
            bf[ci][kt] = *(const short8*)(packB + ((size_t)((w * CPW + ci) * KT + kt) * 64 + l) * 8);

    const int sr = tid >> 2, sub = tid & 3;
    const int snode = min(row0 + sr, N - 1);
    const unsigned short* ap = A + (size_t)snode * 64;
#pragma unroll
    for (int it = 0; it < KT; it++) {
        int d0 = it * 32 + sub * 8;
        short8 v = *(const short8*)(ap + d0);
        *(short8*)&a_pack[(((sr >> 4) * KT + it) * 64 + ((sr & 15) | (sub << 4))) * 8] = v;
    }
    __syncthreads();

    const f32x4 z4 = {0.f, 0.f, 0.f, 0.f};
    f32x4 acc[4][CPW];
#pragma unroll
    for (int m = 0; m < 4; m++)
#pragma unroll
        for (int ci = 0; ci < CPW; ci++) acc[m][ci] = z4;

#pragma unroll
    for (int m = 0; m < 4; m++)
#pragma unroll
        for (int kt = 0; kt < KT; kt++) {
            short8 a = *(const short8*)&a_pack[((m * KT + kt) * 64 + l) * 8];
#pragma unroll
            for (int ci = 0; ci < CPW; ci++)
                acc[m][ci] = __builtin_amdgcn_mfma_f32_16x16x32_bf16(a, bf[ci][kt], acc[m][ci], 0, 0, 0);
        }

    float asrc[CPW], adst[CPW];
#pragma unroll
    for (int ci = 0; ci < CPW; ci++) {
        int cw = w * 64 + ci * 16 + (l & 15);
        asrc[ci] = att_s[cw]; adst[ci] = att_d[cw];
    }
#pragma unroll
    for (int m = 0; m < 4; m++)
#pragma unroll
        for (int q = 0; q < 4; q++) {
            float ps = 0.f, pd = 0.f;
#pragma unroll
            for (int ci = 0; ci < CPW; ci++) {
                ps += acc[m][ci][q] * asrc[ci];
                pd += acc[m][ci][q] * adst[ci];
            }
#pragma unroll
            for (int msk = 1; msk < 16; msk <<= 1) {
                ps += __shfl_xor(ps, msk);
                pd += __shfl_xor(pd, msk);
            }
            int node = row0 + (m << 4) + ((l >> 4) << 2) + q;
            if ((l & 15) == 0 && node < N) {
                aS[node * 4 + w] = ps;
                aD[node * 4 + w] = pd;
            }
#pragma unroll
            for (int ci = 0; ci < CPW; ci++) {
                int col = w * 64 + ci * 16 + (l & 15);
                if (node < N) C[(size_t)node * 256 + col] = f2bf(acc[m][ci][q]);
            }
        }
}

// ---------------------------------------------------------------------------
// GEMM2: xs2[N][64] = h2[N][256] x W2 (+ fused single-head attention logits,
// cross-wave reduction through LDS).
// ---------------------------------------------------------------------------
__launch_bounds__(256, 2)
__global__ void k_gemm2(const unsigned short* __restrict__ A,
                        const unsigned short* __restrict__ packB,
                        const float* __restrict__ att_s, const float* __restrict__ att_d,
                        unsigned short* __restrict__ C,
                        float* __restrict__ aS, float* __restrict__ aD, int N) {
    constexpr int KT = 8;
    __shared__ unsigned short a_pack[4 * KT * 64 * 8];  // 32 KB
    __shared__ float sred[4][64], dred[4][64];

    const int tid = threadIdx.x, w = tid >> 6, l = tid & 63;
    const int row0 = blockIdx.x * 64;

    short8 bf[KT];
#pragma unroll
    for (int kt = 0; kt < KT; kt++)
        bf[kt] = *(const short8*)(packB + ((size_t)(w * KT + kt) * 64 + l) * 8);

    const int sr = tid >> 2, sub = tid & 3;
    const int snode = min(row0 + sr, N - 1);
    const unsigned short* ap = A + (size_t)snode * 256;
#pragma unroll
    for (int it = 0; it < KT; it++) {
        int d0 = it * 32 + sub * 8;
        short8 v = *(const short8*)(ap + d0);
        *(short8*)&a_pack[(((sr >> 4) * KT + it) * 64 + ((sr & 15) | (sub << 4))) * 8] = v;
    }
    __syncthreads();

    const f32x4 z4 = {0.f, 0.f, 0.f, 0.f};
    f32x4 acc[4];
#pragma unroll
    for (int m = 0; m < 4; m++) acc[m] = z4;

#pragma unroll
    for (int m = 0; m < 4; m++)
#pragma unroll
        for (int kt = 0; kt < KT; kt++) {
            short8 a = *(const short8*)&a_pack[((m * KT + kt) * 64 + l) * 8];
            acc[m] = __builtin_amdgcn_mfma_f32_16x16x32_bf16(a, bf[kt], acc[m], 0, 0, 0);
        }

    int colw = w * 16 + (l & 15);
    float asrc = att_s[colw], adst = att_d[colw];
#pragma unroll
    for (int m = 0; m < 4; m++)
#pragma unroll
        for (int q = 0; q < 4; q++) {
            float ps = acc[m][q] * asrc, pd = acc[m][q] * adst;
#pragma unroll
            for (int msk = 1; msk < 16; msk <<= 1) {
                ps += __shfl_xor(ps, msk);
                pd += __shfl_xor(pd, msk);
            }
            if ((l & 15) == 0) {
                int nd = (m << 4) + ((l >> 4) << 2) + q;
                sred[w][nd] = ps; dred[w][nd] = pd;
            }
            int node = row0 + (m << 4) + ((l >> 4) << 2) + q;
            if (node < N) C[(size_t)node * 64 + colw] = f2bf(acc[m][q]);
        }
    __syncthreads();
    if (tid < 64) {
        int node = row0 + tid;
        if (node < N) {
            aS[node] = sred[0][tid] + sred[1][tid] + sred[2][tid] + sred[3][tid];
            aD[node] = dred[0][tid] + dred[1][tid] + dred[2][tid] + dred[3][tid];
        }
    }
}

// --------------------------- CSR build -------------------------------------
__global__ void k_deg(const int* __restrict__ dst, int* __restrict__ deg, int E) {
    int i = blockIdx.x * blockDim.x + threadIdx.x;
    if (i < E) atomicAdd(&deg[dst[i]], 1);
}
// hierarchical scan: per-block inclusive + block sums
__global__ void k_scan1(const int* __restrict__ deg, int* __restrict__ inc,
                        int* __restrict__ bsum, int N) {
    __shared__ int wsum[16];
    int tid = threadIdx.x;
    int i = blockIdx.x * 1024 + tid;
    int v = (i < N) ? deg[i] : 0;
    int lane = tid & 63, wv = tid >> 6;
    int s = v;
#pragma unroll
    for (int d = 1; d < 64; d <<= 1) {
        int t = __shfl_up(s, d);
        if (lane >= d) s += t;
    }
    if (lane == 63) wsum[wv] = s;
    __syncthreads();
    if (tid == 0) {
        int run = 0;
#pragma unroll
        for (int k = 0; k < 16; k++) { int t = wsum[k]; wsum[k] = run; run += t; }
        bsum[blockIdx.x] = run;
    }
    __syncthreads();
    s += wsum[wv];
    if (i < N) inc[i] = s;
}
__global__ void k_scan2(int* __restrict__ bsum, int nb) {
    __shared__ int w0tot;
    int tid = threadIdx.x;
    int v = (tid < nb) ? bsum[tid] : 0;
    int lane = tid & 63, wv = tid >> 6;
    int s = v;
#pragma unroll
    for (int d = 1; d < 64; d <<= 1) {
        int t = __shfl_up(s, d);
        if (lane >= d) s += t;
    }
    if (tid == 63) w0tot = s;
    __syncthreads();
    int ex = s - v + (wv ? w0tot : 0);
    if (tid < nb) bsum[tid] = ex;
}
__global__ void k_scan3(const int* __restrict__ inc, const int* __restrict__ bsum,
                        int* __restrict__ off, int N) {
    int i = blockIdx.x * blockDim.x + threadIdx.x;
    if (i < N) off[i + 1] = inc[i] + bsum[i >> 10];
    if (i == 0) off[0] = 0;
}
__global__ void k_fill(const int* __restrict__ srcv, const int* __restrict__ dstv,
                       const int* __restrict__ off, int* __restrict__ cursor,
                       int* __restrict__ ssrc, int E) {
    int i = blockIdx.x * blockDim.x + threadIdx.x;
    if (i < E) {
        int d = dstv[i];
        int pos = off[d] + atomicAdd(&cursor[d], 1);
        ssrc[pos] = srcv[i];
    }
}

// ---------------------------------------------------------------------------
// GAT layer-1 aggregation (H=4, C=64). Wave per dst node; 1-deep prefetch.
// ---------------------------------------------------------------------------
__global__ void k_agg1(const unsigned short* __restrict__ xs,
                       const float* __restrict__ a_s, const float* __restrict__ a_d,
                       const int* __restrict__ off, const int* __restrict__ ssrc,
                       const float* __restrict__ bias,
                       unsigned short* __restrict__ out, int N) {
    int v = blockIdx.x * 4 + (threadIdx.x >> 6);
    if (v >= N) return;
    int l = threadIdx.x & 63;
    int h = l >> 4;
    int c0 = l * 4;
    float adv = a_d[v * 4 + h];
    float e = lrelu(a_s[v * 4 + h] + adv);
    float m = e, s = 1.0f;
    us4 xv = *(const us4*)(xs + (size_t)v * 256 + c0);
    float a0 = bf2f(xv[0]), a1 = bf2f(xv[1]), a2 = bf2f(xv[2]), a3 = bf2f(xv[3]);
    int beg = off[v], end = off[v + 1];
    float as_c = 0.f; us4 x_c = {0, 0, 0, 0};
    if (beg < end) {
        int u = ssrc[beg];
        as_c = a_s[u * 4 + h];
        x_c = *(const us4*)(xs + (size_t)u * 256 + c0);
    }
    for (int idx = beg; idx < end; idx++) {
        float as_n = 0.f; us4 x_n = {0, 0, 0, 0};
        if (idx + 1 < end) {
            int u = ssrc[idx + 1];
            as_n = a_s[u * 4 + h];
            x_n = *(const us4*)(xs + (size_t)u * 256 + c0);
        }
        float eu = lrelu(as_c + adv);
        float mn = fmaxf(m, eu);
        float cm = __expf(m - mn), ce = __expf(eu - mn);
        s = s * cm + ce;
        a0 = a0 * cm + ce * bf2f(x_c[0]);
        a1 = a1 * cm + ce * bf2f(x_c[1]);
        a2 = a2 * cm + ce * bf2f(x_c[2]);
        a3 = a3 * cm + ce * bf2f(x_c[3]);
        m = mn;
        as_c = as_n; x_c = x_n;
    }
    float inv = __builtin_amdgcn_rcpf(s + 1e-16f);
    us4 ov;
    ov[0] = f2bf(fmaxf(a0 * inv + bias[c0 + 0], 0.f));
    ov[1] = f2bf(fmaxf(a1 * inv + bias[c0 + 1], 0.f));
    ov[2] = f2bf(fmaxf(a2 * inv + bias[c0 + 2], 0.f));
    ov[3] = f2bf(fmaxf(a3 * inv + bias[c0 + 3], 0.f));
    *(us4*)(out + (size_t)v * 256 + c0) = ov;
}

// GAT layer-2 aggregation (H=1, C=64). Wave per node; 1-deep prefetch.
__global__ void k_agg2(const unsigned short* __restrict__ xs,
                       const float* __restrict__ a_s, const float* __restrict__ a_d,
                       const int* __restrict__ off, const int* __restrict__ ssrc,
                       const float* __restrict__ bias,
                       float* __restrict__ out, int N) {
    int v = blockIdx.x * 4 + (threadIdx.x >> 6);
    if (v >= N) return;
    int l = threadIdx.x & 63;
    float adv = a_d[v];
    float e = lrelu(a_s[v] + adv);
    float m = e, s = 1.0f;
    float acc = bf2f(xs[(size_t)v * 64 + l]);
    int beg = off[v], end = off[v + 1];
    float as_c = 0.f; float x_c = 0.f;
    if (beg < end) {
        int u = ssrc[beg];
        as_c = a_s[u];
        x_c = bf2f(xs[(size_t)u * 64 + l]);
    }
    for (int idx = beg; idx < end; idx++) {
        float as_n = 0.f, x_n = 0.f;
        if (idx + 1 < end) {
            int u = ssrc[idx + 1];
            as_n = a_s[u];
            x_n = bf2f(xs[(size_t)u * 64 + l]);
        }
        float eu = lrelu(as_c + adv);
        float mn = fmaxf(m, eu);
        float cm = __expf(m - mn), ce = __expf(eu - mn);
        s = s * cm + ce;
        acc = acc * cm + ce * x_c;
        m = mn;
        as_c = as_n; x_c = x_n;
    }
    float o = acc * __builtin_amdgcn_rcpf(s + 1e-16f) + bias[l];
    out[(size_t)v * 64 + l] = fmaxf(o, 0.f);
}

// --------------------------- pooling + FC ----------------------------------
__global__ void k_bounds(const int* __restrict__ batch, int* __restrict__ start, int N, int G) {
    int g = blockIdx.x * blockDim.x + threadIdx.x;
    if (g > G) return;
    int lo = 0, hi = N;
    while (lo < hi) {
        int mid = (lo + hi) >> 1;
        if (batch[mid] < g) lo = mid + 1; else hi = mid;
    }
    start[g] = lo;
}
__global__ void k_pool(const float* __restrict__ h3, const int* __restrict__ start,
                       const float* __restrict__ fc_w, const float* __restrict__ fc_b,
                       float* __restrict__ out, int G) {
    __shared__ float red[4][64];
    __shared__ float meanv[64];
    __shared__ float lg[10];
    int g = blockIdx.x;
    int tid = threadIdx.x, c = tid & 63, ro = tid >> 6;
    int s0 = start[g], s1 = start[g + 1];
    float p = 0.f;
    for (int r = s0 + ro; r < s1; r += 4) p += h3[(size_t)r * 64 + c];
    red[ro][c] = p;
    __syncthreads();
    if (tid < 64) {
        float tot = red[0][c] + red[1][c] + red[2][c] + red[3][c];
        float cnt = (float)max(s1 - s0, 1);
        meanv[c] = tot / cnt;
    }
    __syncthreads();
    if (tid < 10) {
        float lv = fc_b[tid];
        for (int k = 0; k < 64; k++) lv += meanv[k] * fc_w[k * 10 + tid];
        lg[tid] = lv;
    }
    __syncthreads();
    if (tid == 0) {
        float mx = lg[0];
        for (int k = 1; k < 10; k++) mx = fmaxf(mx, lg[k]);
        float ss = 0.f;
        for (int k = 0; k < 10; k++) ss += expf(lg[k] - mx);
        float lse = mx + logf(ss);
        for (int k = 0; k < 10; k++) out[g * 10 + k] = lg[k] - lse;
    }
}

// ---------------------------------------------------------------------------
extern "C" void kernel_launch(void* const* d_in, const int* in_sizes, int n_in,
                              void* d_out, int out_size, void* d_ws, size_t ws_size,
                              hipStream_t stream) {
    const float* x = (const float*)d_in[0];
    const int* ei = (const int*)d_in[1];
    const int* batch = (const int*)d_in[2];
    const float* w_ih = (const float*)d_in[4];
    const float* w_hh = (const float*)d_in[5];
    const float* b_ih = (const float*)d_in[6];
    const float* b_hh = (const float*)d_in[7];
    const float* W1 = (const float*)d_in[8];
    const float* as1 = (const float*)d_in[9];
    const float* ad1 = (const float*)d_in[10];
    const float* b1 = (const float*)d_in[11];
    const float* W2 = (const float*)d_in[12];
    const float* as2 = (const float*)d_in[13];
    const float* ad2 = (const float*)d_in[14];
    const float* b2 = (const float*)d_in[15];
    const float* fc_w = (const float*)d_in[18];
    const float* fc_b = (const float*)d_in[19];
    float* out = (float*)d_out;

    const int N = in_sizes[0] / (8 * 128);   // 100000
    const int E = in_sizes[1] / 2;           // 1600000
    const int G = 128;

    char* ws = (char*)d_ws;
    size_t cur = 0;
    auto alloc = [&](size_t b) { size_t r = cur; cur += (b + 255) & ~(size_t)255; return r; };
    unsigned short* p_gi = (unsigned short*)(ws + alloc((size_t)12 * 4 * 64 * 8 * 2));
    unsigned short* p_gh = (unsigned short*)(ws + alloc((size_t)12 * 2 * 64 * 8 * 2));
    unsigned short* p_w1 = (unsigned short*)(ws + alloc((size_t)16 * 2 * 64 * 8 * 2));
    unsigned short* p_w2 = (unsigned short*)(ws + alloc((size_t)4 * 8 * 64 * 8 * 2));
    unsigned short* h1 = (unsigned short*)(ws + alloc((size_t)N * 64 * 2));
    unsigned short* xs1 = (unsigned short*)(ws + alloc((size_t)N * 256 * 2));  // reused as xs2
    unsigned short* h2 = (unsigned short*)(ws + alloc((size_t)N * 256 * 2));
    float* h3 = (float*)(ws + alloc((size_t)N * 64 * 4));
    float* aS = (float*)(ws + alloc((size_t)N * 4 * 4));
    float* aD = (float*)(ws + alloc((size_t)N * 4 * 4));
    int* deg = (int*)(ws + alloc((size_t)N * 4));       // reused as cursor
    int* offp = (int*)(ws + alloc((size_t)(N + 1) * 4));
    int* inc = (int*)(ws + alloc((size_t)N * 4));
    int* bsum = (int*)(ws + alloc((size_t)128 * 4));
    int* ssrc = (int*)(ws + alloc((size_t)E * 4));
    int* startb = (int*)(ws + alloc((size_t)(G + 1) * 4));

    // ---- weight packing ----
    k_pack<<<12, 256, 0, stream>>>(w_ih, p_gi, 128, 192, 128, 1);
    k_pack<<<6, 256, 0, stream>>>(w_hh, p_gh, 64, 192, 64, 1);
    k_pack<<<8, 256, 0, stream>>>(W1, p_w1, 64, 256, 256, 0);
    k_pack<<<8, 256, 0, stream>>>(W2, p_w2, 256, 64, 64, 0);

    // ---- CSR by dst ----
    const int nbscan = (N + 1023) / 1024;  // 98
    hipMemsetAsync(deg, 0, (size_t)N * 4, stream);
    k_deg<<<(E + 255) / 256, 256, 0, stream>>>(ei + E, deg, E);
    k_scan1<<<nbscan, 1024, 0, stream>>>(deg, inc, bsum, N);
    k_scan2<<<1, 128, 0, stream>>>(bsum, nbscan);
    k_scan3<<<(N + 255) / 256, 256, 0, stream>>>(inc, bsum, offp, N);
    hipMemsetAsync(deg, 0, (size_t)N * 4, stream);  // reuse as cursor
    k_fill<<<(E + 255) / 256, 256, 0, stream>>>(ei, ei + E, offp, deg, ssrc, E);

    const int nb64 = (N + 63) / 64;
    const int nb4 = (N + 3) / 4;

    // ---- GRU ----
    k_gru<<<nb64, 256, 0, stream>>>(x, p_gi, p_gh, b_ih, b_hh, h1, N);

    // ---- GAT layer 1 (att fused into GEMM epilogue) ----
    k_gemm1<<<nb64, 256, 0, stream>>>(h1, p_w1, as1, ad1, xs1, aS, aD, N);
    k_agg1<<<nb4, 256, 0, stream>>>(xs1, aS, aD, offp, ssrc, b1, h2, N);

    // ---- GAT layer 2 ----
    k_gemm2<<<nb64, 256, 0, stream>>>(h2, p_w2, as2, ad2, xs1 /*xs2*/, aS, aD, N);
    k_agg2<<<nb4, 256, 0, stream>>>(xs1, aS, aD, offp, ssrc, b2, h3, N);

    // ---- pooling + FC + log_softmax (aw == 1 exactly; attn_w/b unused) ----
    k_bounds<<<1, 256, 0, stream>>>(batch, startb, N, G);
    k_pool<<<G, 256, 0, stream>>>(h3, startb, fc_w, fc_b, out, G);
}

// Round 3
// 571.733 us; speedup vs baseline: 1.8647x; 1.3069x over previous
//
#include <hip/hip_runtime.h>
#include <stdint.h>

// ---------------------------------------------------------------------------
// DAGNN: GRU(128->64, T=8) -> GATConv(64->4x64, concat) -> GATConv(256->64)
//        -> segment-mean pool -> FC(64->10) -> log_softmax
// R3: two-pass (max, then fixed-max accumulate) GAT aggregation with deep
// static-slot pipelining; attention logits folded into GEMM as extra MFMA
// columns (a_src = h·(W@att_src)); v_cvt_pk_bf16_f32 conversions; fused
// pack dispatcher; bounds folded into pool.
// ---------------------------------------------------------------------------

typedef __attribute__((ext_vector_type(8))) short short8;
typedef __attribute__((ext_vector_type(4))) float f32x4;
typedef __attribute__((ext_vector_type(4))) unsigned short us4;
typedef __attribute__((ext_vector_type(8))) unsigned short us8;
typedef __attribute__((ext_vector_type(4))) unsigned int u32x4;

__device__ __forceinline__ unsigned short f2bf(float f) {   // RNE (cold paths)
    unsigned u = __float_as_uint(f);
    u += 0x7FFFu + ((u >> 16) & 1u);
    return (unsigned short)(u >> 16);
}
__device__ __forceinline__ float bf2f(unsigned short h) {
    return __uint_as_float(((unsigned)h) << 16);
}
__device__ __forceinline__ unsigned cvtpk(float lo, float hi) {  // 2xf32->2xbf16, 1 op
    unsigned r;
    asm("v_cvt_pk_bf16_f32 %0, %1, %2" : "=v"(r) : "v"(lo), "v"(hi));
    return r;
}
__device__ __forceinline__ unsigned short f2bfq(float v) {       // f32->bf16, 1 op
    unsigned r;
    asm("v_cvt_pk_bf16_f32 %0, %1, %1" : "=v"(r) : "v"(v));
    return (unsigned short)r;
}
__device__ __forceinline__ float lrelu(float x) { return x > 0.f ? x : 0.2f * x; }
__device__ __forceinline__ float fsig(float a) {
    return __builtin_amdgcn_rcpf(1.f + __expf(-a));
}
__device__ __forceinline__ float ftanh(float a) {
    return 2.f * __builtin_amdgcn_rcpf(1.f + __expf(-2.f * a)) - 1.f;
}

// ---------------------------------------------------------------------------
// Weight prep (one dispatcher kernel).
// B-frag layout: frag f = ct*KT + kt; elem [f][lane][i] = B[k][col],
//   col = ct*16 + (lane&15), k = kt*32 + (lane>>4)*8 + i
// ---------------------------------------------------------------------------
__device__ void pack_body(const float* __restrict__ src, unsigned short* __restrict__ dst,
                          int K, int NCOL, int ldsrc, int transposed, int blk, int tid) {
    int id = blk * 256 + tid;
    int KT = K >> 5;
    int nfrag = (NCOL >> 4) * KT;
    if (id >= nfrag * 64) return;
    int l = id & 63;
    int f = id >> 6;
    int kt = f % KT, ct = f / KT;
    int col = ct * 16 + (l & 15);
    int kbase = kt * 32 + ((l >> 4) << 3);
#pragma unroll
    for (int i = 0; i < 8; i++) {
        int k = kbase + i;
        float v = transposed ? src[(size_t)col * ldsrc + k] : src[(size_t)k * ldsrc + col];
        dst[((size_t)f * 64 + l) * 8 + i] = f2bf(v);
    }
}
// wa[k][col] = col<2H ? sum_c W[k, (col>>1)*64+c] * att[col>>1][c] : 0
__device__ void packv_body(const float* __restrict__ W, const float* __restrict__ avs,
                           const float* __restrict__ avd, unsigned short* __restrict__ dst,
                           int K, int H, int ldW, int blk, int tid) {
    int id = blk * 256 + tid;
    int KT = K >> 5;
    if (id >= KT * 64) return;
    int l = id & 63, f = id >> 6;  // f = kt
    int col = l & 15;
    int kbase = f * 32 + ((l >> 4) << 3);
    for (int i = 0; i < 8; i++) {
        int k = kbase + i;
        float val = 0.f;
        if (col < 2 * H) {
            int h = col >> 1;
            const float* av = (col & 1) ? avd : avs;
            for (int c = 0; c < 64; c++) val += W[(size_t)k * ldW + h * 64 + c] * av[h * 64 + c];
        }
        dst[((size_t)f * 64 + l) * 8 + i] = f2bf(val);
    }
}
__global__ void k_prep(const float* w_ih, const float* w_hh, const float* W1, const float* W2,
                       const float* as1, const float* ad1, const float* as2, const float* ad2,
                       unsigned short* p_gi, unsigned short* p_gh,
                       unsigned short* p_w1, unsigned short* p_w2,
                       unsigned short* p_v1, unsigned short* p_v2) {
    int b = blockIdx.x, tid = threadIdx.x;
    if (b < 12)      pack_body(w_ih, p_gi, 128, 192, 128, 1, b, tid);
    else if (b < 18) pack_body(w_hh, p_gh, 64, 192, 64, 1, b - 12, tid);
    else if (b < 26) pack_body(W1, p_w1, 64, 256, 256, 0, b - 18, tid);
    else if (b < 34) pack_body(W2, p_w2, 256, 64, 64, 0, b - 26, tid);
    else if (b < 35) packv_body(W1, as1, ad1, p_v1, 64, 4, 256, b - 34, tid);
    else             packv_body(W2, as2, ad2, p_v2, 256, 1, 64, b - 35, tid);
}

// ---------------------------------------------------------------------------
// Fused GRU. Block = 64 nodes, 256 threads (4 waves). Wave w owns hidden
// columns [16w,16w+16). x prefetched 1 step ahead; cvt_pk conversions.
// ---------------------------------------------------------------------------
__launch_bounds__(256, 2)
__global__ void k_gru(const float* __restrict__ x,
                      const unsigned short* __restrict__ pgi,
                      const unsigned short* __restrict__ pgh,
                      const float* __restrict__ b_ih, const float* __restrict__ b_hh,
                      unsigned short* __restrict__ h1, int N) {
    __shared__ unsigned short x_pack[4 * 4 * 64 * 8];  // 16 KB
    __shared__ unsigned short h_pack[4 * 2 * 64 * 8];  // 8 KB

    const int tid = threadIdx.x;
    const int w = tid >> 6;
    const int l = tid & 63;
    const int row0 = blockIdx.x * 64;

    short8 wgi[3][4], wgh[3][2];
#pragma unroll
    for (int g = 0; g < 3; g++) {
        int ctg = g * 4 + w;
#pragma unroll
        for (int kt = 0; kt < 4; kt++)
            wgi[g][kt] = *(const short8*)(pgi + ((size_t)(ctg * 4 + kt) * 64 + l) * 8);
#pragma unroll
        for (int kt = 0; kt < 2; kt++)
            wgh[g][kt] = *(const short8*)(pgh + ((size_t)(ctg * 2 + kt) * 64 + l) * 8);
    }
    const int j = (w << 4) + (l & 15);
    const float bs_r = b_ih[j] + b_hh[j];
    const float bs_z = b_ih[64 + j] + b_hh[64 + j];
    const float bi_n = b_ih[128 + j], bh_n = b_hh[128 + j];

    f32x4 hreg[4];
    const f32x4 z4 = {0.f, 0.f, 0.f, 0.f};
#pragma unroll
    for (int m = 0; m < 4; m++) hreg[m] = z4;

    const int sr = tid >> 2, sub = tid & 3;
    const int snode = min(row0 + sr, N - 1);
    const int slane = (sr & 15) | (sub << 4);
    const int sm = sr >> 4;
    const float* xbase = x + (size_t)snode * 1024;

    float4 pre[8];
#pragma unroll
    for (int it = 0; it < 4; it++) {
        int d0 = it * 32 + sub * 8;
        pre[2 * it] = *(const float4*)(xbase + d0);
        pre[2 * it + 1] = *(const float4*)(xbase + d0 + 4);
    }

    for (int t = 0; t < 8; t++) {
        u32x4 pk[4];
#pragma unroll
        for (int it = 0; it < 4; it++) {
            float4 va = pre[2 * it], vb = pre[2 * it + 1];
            u32x4 p;
            p[0] = cvtpk(va.x, va.y); p[1] = cvtpk(va.z, va.w);
            p[2] = cvtpk(vb.x, vb.y); p[3] = cvtpk(vb.z, vb.w);
            pk[it] = p;
        }
        if (t > 0) {
#pragma unroll
            for (int m = 0; m < 4; m++)
#pragma unroll
                for (int q = 0; q < 4; q++) {
                    int rl = ((l >> 4) << 2) + q;
                    int lane2 = rl | (((j >> 3) & 3) << 4);
                    h_pack[((m * 2 + (j >> 5)) * 64 + lane2) * 8 + (j & 7)] = f2bfq(hreg[m][q]);
                }
        }
#pragma unroll
        for (int it = 0; it < 4; it++)
            *(u32x4*)&x_pack[((sm * 4 + it) * 64 + slane) * 8] = pk[it];
        __syncthreads();

        if (t < 7) {
            const float* xp = xbase + (t + 1) * 128;
#pragma unroll
            for (int it = 0; it < 4; it++) {
                int d0 = it * 32 + sub * 8;
                pre[2 * it] = *(const float4*)(xp + d0);
                pre[2 * it + 1] = *(const float4*)(xp + d0 + 4);
            }
        }

        f32x4 agi[4][3], aghn[4];
#pragma unroll
        for (int m = 0; m < 4; m++) {
            agi[m][0] = z4; agi[m][1] = z4; agi[m][2] = z4; aghn[m] = z4;
        }

#pragma unroll
        for (int m = 0; m < 4; m++) {
#pragma unroll
            for (int kt = 0; kt < 4; kt++) {
                short8 a = *(const short8*)&x_pack[((m * 4 + kt) * 64 + l) * 8];
#pragma unroll
                for (int g = 0; g < 3; g++)
                    agi[m][g] = __builtin_amdgcn_mfma_f32_16x16x32_bf16(a, wgi[g][kt], agi[m][g], 0, 0, 0);
            }
            if (t > 0) {
#pragma unroll
                for (int kt = 0; kt < 2; kt++) {
                    short8 a = *(const short8*)&h_pack[((m * 2 + kt) * 64 + l) * 8];
                    agi[m][0] = __builtin_amdgcn_mfma_f32_16x16x32_bf16(a, wgh[0][kt], agi[m][0], 0, 0, 0);
                    agi[m][1] = __builtin_amdgcn_mfma_f32_16x16x32_bf16(a, wgh[1][kt], agi[m][1], 0, 0, 0);
                    aghn[m]   = __builtin_amdgcn_mfma_f32_16x16x32_bf16(a, wgh[2][kt], aghn[m], 0, 0, 0);
                }
            }
        }
#pragma unroll
        for (int m = 0; m < 4; m++) {
#pragma unroll
            for (int q = 0; q < 4; q++) {
                float rr = fsig(agi[m][0][q] + bs_r);
                float zz = fsig(agi[m][1][q] + bs_z);
                float hn = aghn[m][q] + bh_n;
                float nn = ftanh(agi[m][2][q] + bi_n + rr * hn);
                hreg[m][q] = nn + zz * (hreg[m][q] - nn);
            }
        }
        __syncthreads();
    }
#pragma unroll
    for (int m = 0; m < 4; m++)
#pragma unroll
        for (int q = 0; q < 4; q++) {
            int node = row0 + (m << 4) + ((l >> 4) << 2) + q;
            if (node < N) h1[(size_t)node * 64 + j] = f2bfq(hreg[m][q]);
        }
}

// ---------------------------------------------------------------------------
// GEMM1: xs1[N][256] = h1[N][64] x W1; logits via extra MFMA columns.
// ---------------------------------------------------------------------------
__launch_bounds__(256, 2)
__global__ void k_gemm1(const unsigned short* __restrict__ A,
                        const unsigned short* __restrict__ packB,
                        const unsigned short* __restrict__ pv1,
                        unsigned short* __restrict__ C,
                        float* __restrict__ aS, float* __restrict__ aD, int N) {
    constexpr int KT = 2, CPW = 4;
    __shared__ unsigned short a_pack[4 * KT * 64 * 8];

    const int tid = threadIdx.x, w = tid >> 6, l = tid & 63;
    const int row0 = blockIdx.x * 64;

    short8 bf[CPW][KT];
#pragma unroll
    for (int ci = 0; ci < CPW; ci++)
#pragma unroll
        for (int kt = 0; kt < KT; kt++)
            bf[ci][kt] = *(const short8*)(packB + ((size_t)((w * CPW + ci) * KT + kt) * 64 + l) * 8);

    const int sr = tid >> 2, sub = tid & 3;
    const int snode = min(row0 + sr, N - 1);
    const unsigned short* ap = A + (size_t)snode * 64;
#pragma unroll
    for (int it = 0; it < KT; it++) {
        int d0 = it * 32 + sub * 8;
        short8 v = *(const short8*)(ap + d0);
        *(short8*)&a_pack[(((sr >> 4) * KT + it) * 64 + ((sr & 15) | (sub << 4))) * 8] = v;
    }
    __syncthreads();

    const f32x4 z4 = {0.f, 0.f, 0.f, 0.f};
    f32x4 acc[4][CPW];
#pragma unroll
    for (int m = 0; m < 4; m++)
#pragma unroll
        for (int ci = 0; ci < CPW; ci++) acc[m][ci] = z4;

#pragma unroll
    for (int m = 0; m < 4; m++)
#pragma unroll
        for (int kt = 0; kt < KT; kt++) {
            short8 a = *(const short8*)&a_pack[((m * KT + kt) * 64 + l) * 8];
#pragma unroll
            for (int ci = 0; ci < CPW; ci++)
                acc[m][ci] = __builtin_amdgcn_mfma_f32_16x16x32_bf16(a, bf[ci][kt], acc[m][ci], 0, 0, 0);
        }

    // logit tile: wave w handles m-tile w
    f32x4 acce = z4;
#pragma unroll
    for (int kt = 0; kt < KT; kt++) {
        short8 be = *(const short8*)(pv1 + ((size_t)kt * 64 + l) * 8);
        short8 a = *(const short8*)&a_pack[((w * KT + kt) * 64 + l) * 8];
        acce = __builtin_amdgcn_mfma_f32_16x16x32_bf16(a, be, acce, 0, 0, 0);
    }
    int colE = l & 15;
    if (colE < 8) {
        int h = colE >> 1;
#pragma unroll
        for (int q = 0; q < 4; q++) {
            int node = row0 + (w << 4) + ((l >> 4) << 2) + q;
            if (node < N) {
                if (colE & 1) aD[node * 4 + h] = acce[q];
                else          aS[node * 4 + h] = acce[q];
            }
        }
    }

#pragma unroll
    for (int m = 0; m < 4; m++)
#pragma unroll
        for (int ci = 0; ci < CPW; ci++)
#pragma unroll
            for (int q = 0; q < 4; q++) {
                int node = row0 + (m << 4) + ((l >> 4) << 2) + q;
                int col = w * 64 + ci * 16 + (l & 15);
                if (node < N) C[(size_t)node * 256 + col] = f2bfq(acc[m][ci][q]);
            }
}

// ---------------------------------------------------------------------------
// GEMM2: xs2[N][64] = h2[N][256] x W2; logits via extra MFMA columns.
// ---------------------------------------------------------------------------
__launch_bounds__(256, 2)
__global__ void k_gemm2(const unsigned short* __restrict__ A,
                        const unsigned short* __restrict__ packB,
                        const unsigned short* __restrict__ pv2,
                        unsigned short* __restrict__ C,
                        float* __restrict__ aS, float* __restrict__ aD, int N) {
    constexpr int KT = 8;
    __shared__ unsigned short a_pack[4 * KT * 64 * 8];  // 32 KB

    const int tid = threadIdx.x, w = tid >> 6, l = tid & 63;
    const int row0 = blockIdx.x * 64;

    short8 bf[KT];
#pragma unroll
    for (int kt = 0; kt < KT; kt++)
        bf[kt] = *(const short8*)(packB + ((size_t)(w * KT + kt) * 64 + l) * 8);

    const int sr = tid >> 2, sub = tid & 3;
    const int snode = min(row0 + sr, N - 1);
    const unsigned short* ap = A + (size_t)snode * 256;
#pragma unroll
    for (int it = 0; it < KT; it++) {
        int d0 = it * 32 + sub * 8;
        short8 v = *(const short8*)(ap + d0);
        *(short8*)&a_pack[(((sr >> 4) * KT + it) * 64 + ((sr & 15) | (sub << 4))) * 8] = v;
    }
    __syncthreads();

    const f32x4 z4 = {0.f, 0.f, 0.f, 0.f};
    f32x4 acc[4];
#pragma unroll
    for (int m = 0; m < 4; m++) acc[m] = z4;

#pragma unroll
    for (int m = 0; m < 4; m++)
#pragma unroll
        for (int kt = 0; kt < KT; kt++) {
            short8 a = *(const short8*)&a_pack[((m * KT + kt) * 64 + l) * 8];
            acc[m] = __builtin_amdgcn_mfma_f32_16x16x32_bf16(a, bf[kt], acc[m], 0, 0, 0);
        }

    // logit tile: wave w handles m-tile w
    f32x4 acce = z4;
#pragma unroll
    for (int kt = 0; kt < KT; kt++) {
        short8 be = *(const short8*)(pv2 + ((size_t)kt * 64 + l) * 8);
        short8 a = *(const short8*)&a_pack[((w * KT + kt) * 64 + l) * 8];
        acce = __builtin_amdgcn_mfma_f32_16x16x32_bf16(a, be, acce, 0, 0, 0);
    }
    int colE = l & 15;
    if (colE < 2) {
#pragma unroll
        for (int q = 0; q < 4; q++) {
            int node = row0 + (w << 4) + ((l >> 4) << 2) + q;
            if (node < N) {
                if (colE) aD[node] = acce[q];
                else      aS[node] = acce[q];
            }
        }
    }

    int colw = w * 16 + (l & 15);
#pragma unroll
    for (int m = 0; m < 4; m++)
#pragma unroll
        for (int q = 0; q < 4; q++) {
            int node = row0 + (m << 4) + ((l >> 4) << 2) + q;
            if (node < N) C[(size_t)node * 64 + colw] = f2bfq(acc[m][q]);
        }
}

// --------------------------- CSR build -------------------------------------
__global__ void k_deg(const int* __restrict__ dst, int* __restrict__ deg, int E) {
    int i = blockIdx.x * blockDim.x + threadIdx.x;
    if (i < E) atomicAdd(&deg[dst[i]], 1);
}
__global__ void k_scan1(const int* __restrict__ deg, int* __restrict__ inc,
                        int* __restrict__ bsum, int N) {
    __shared__ int wsum[16];
    int tid = threadIdx.x;
    int i = blockIdx.x * 1024 + tid;
    int v = (i < N) ? deg[i] : 0;
    int lane = tid & 63, wv = tid >> 6;
    int s = v;
#pragma unroll
    for (int d = 1; d < 64; d <<= 1) {
        int t = __shfl_up(s, d);
        if (lane >= d) s += t;
    }
    if (lane == 63) wsum[wv] = s;
    __syncthreads();
    if (tid == 0) {
        int run = 0;
#pragma unroll
        for (int k = 0; k < 16; k++) { int t = wsum[k]; wsum[k] = run; run += t; }
        bsum[blockIdx.x] = run;
    }
    __syncthreads();
    s += wsum[wv];
    if (i < N) inc[i] = s;
}
__global__ void k_scan2(int* __restrict__ bsum, int nb) {
    __shared__ int w0tot;
    int tid = threadIdx.x;
    int v = (tid < nb) ? bsum[tid] : 0;
    int lane = tid & 63, wv = tid >> 6;
    int s = v;
#pragma unroll
    for (int d = 1; d < 64; d <<= 1) {
        int t = __shfl_up(s, d);
        if (lane >= d) s += t;
    }
    if (tid == 63) w0tot = s;
    __syncthreads();
    int ex = s - v + (wv ? w0tot : 0);
    if (tid < nb) bsum[tid] = ex;
}
__global__ void k_scan3(const int* __restrict__ inc, const int* __restrict__ bsum,
                        int* __restrict__ off, int N) {
    int i = blockIdx.x * blockDim.x + threadIdx.x;
    if (i < N) off[i + 1] = inc[i] + bsum[i >> 10];
    if (i == 0) off[0] = 0;
}
__global__ void k_fill(const int* __restrict__ srcv, const int* __restrict__ dstv,
                       const int* __restrict__ off, int* __restrict__ cursor,
                       int* __restrict__ ssrc, int E) {
    int i = blockIdx.x * blockDim.x + threadIdx.x;
    if (i < E) {
        int d = dstv[i];
        int pos = off[d] + atomicAdd(&cursor[d], 1);
        ssrc[pos] = srcv[i];
    }
}

// ---------------------------------------------------------------------------
// GAT layer-1 aggregation (H=4, C=256 concat). Wave per dst node.
// Pass 1: per-head max. Pass 2: fixed-max accumulate, half-wave per edge
// (2 edges/iter, 16 B/lane), 3 static slots (6 edges in flight).
// ---------------------------------------------------------------------------
__global__ void k_agg1(const unsigned short* __restrict__ xs,
                       const float* __restrict__ a_s, const float* __restrict__ a_d,
                       const int* __restrict__ off, const int* __restrict__ ssrc,
                       const float* __restrict__ bias,
                       unsigned short* __restrict__ out, int N) {
    int v = blockIdx.x * 4 + (threadIdx.x >> 6);
    if (v >= N) return;
    const int l = threadIdx.x & 63;
    const int beg = off[v], end = off[v + 1];
    const int cnt = end - beg;

    // ---- pass 1: per-head max (lane = e*4 + hh) ----
    const int hh = l & 3;
    const float advh = a_d[v * 4 + hh];
    float mx = lrelu(a_s[v * 4 + hh] + advh);
    for (int idx = beg + (l >> 2); idx < end; idx += 16) {
        int u = ssrc[idx];
        mx = fmaxf(mx, lrelu(a_s[u * 4 + hh] + advh));
    }
#pragma unroll
    for (int msk = 4; msk < 64; msk <<= 1) mx = fmaxf(mx, __shfl_xor(mx, msk));

    // ---- pass 2 ----
    const int ep = l >> 5;       // which edge of the pair
    const int cq = l & 31;       // channel octet
    const int h4 = cq >> 3;
    const float m = __shfl(mx, h4);
    const float adv = a_d[v * 4 + h4];
    const int c0 = cq * 8;

    float s_;
    float ac[8];
    {
        us8 xv = *(const us8*)(xs + (size_t)v * 256 + c0);
        float pv = (ep == 0) ? __expf(lrelu(a_s[v * 4 + h4] + adv) - m) : 0.f;
        s_ = pv;
#pragma unroll
        for (int i = 0; i < 8; i++) ac[i] = pv * bf2f(xv[i]);
    }

#define AG1_LOAD(S, POS) { int pp = min((POS) + ep, cl); int uu = ssrc[beg + pp]; \
        aa##S = a_s[uu * 4 + h4]; x##S = *(const us8*)(xs + (size_t)uu * 256 + c0); }
#define AG1_PROC(S) { float p = __expf(lrelu(aa##S + adv) - m); s_ += p; \
        _Pragma("unroll") for (int i = 0; i < 8; i++) ac[i] += p * bf2f(x##S[i]); }

    float aa0 = 0.f, aa1 = 0.f, aa2 = 0.f;
    us8 x0 = {0}, x1 = {0}, x2 = {0};
    int k = 0;
    if (cnt > 0) {
        const int cl = cnt - 1;
        AG1_LOAD(0, 0) AG1_LOAD(1, 2) AG1_LOAD(2, 4)
        for (; k + 6 <= cnt; k += 6) {
            AG1_PROC(0) AG1_LOAD(0, k + 6)
            AG1_PROC(1) AG1_LOAD(1, k + 8)
            AG1_PROC(2) AG1_LOAD(2, k + 10)
        }
        if (k + ep < cnt)     AG1_PROC(0)
        if (k + 2 + ep < cnt) AG1_PROC(1)
        if (k + 4 + ep < cnt) AG1_PROC(2)
    }
#undef AG1_LOAD
#undef AG1_PROC

    s_ += __shfl_xor(s_, 32);
#pragma unroll
    for (int i = 0; i < 8; i++) ac[i] += __shfl_xor(ac[i], 32);

    if (ep == 0) {
        float inv = __builtin_amdgcn_rcpf(s_ + 1e-16f);
        float4 b4a = *(const float4*)(bias + c0);
        float4 b4b = *(const float4*)(bias + c0 + 4);
        float r0 = fmaxf(ac[0] * inv + b4a.x, 0.f), r1 = fmaxf(ac[1] * inv + b4a.y, 0.f);
        float r2 = fmaxf(ac[2] * inv + b4a.z, 0.f), r3 = fmaxf(ac[3] * inv + b4a.w, 0.f);
        float r4 = fmaxf(ac[4] * inv + b4b.x, 0.f), r5 = fmaxf(ac[5] * inv + b4b.y, 0.f);
        float r6 = fmaxf(ac[6] * inv + b4b.z, 0.f), r7 = fmaxf(ac[7] * inv + b4b.w, 0.f);
        u32x4 ov;
        ov[0] = cvtpk(r0, r1); ov[1] = cvtpk(r2, r3);
        ov[2] = cvtpk(r4, r5); ov[3] = cvtpk(r6, r7);
        *(u32x4*)(out + (size_t)v * 256 + c0) = ov;
    }
}

// ---------------------------------------------------------------------------
// GAT layer-2 aggregation (H=1, C=64). Wave per node; quarter-wave per edge
// (4 edges/iter, 8 B/lane), 2 static slots (8 edges in flight).
// ---------------------------------------------------------------------------
__global__ void k_agg2(const unsigned short* __restrict__ xs,
                       const float* __restrict__ a_s, const float* __restrict__ a_d,
                       const int* __restrict__ off, const int* __restrict__ ssrc,
                       const float* __restrict__ bias,
                       float* __restrict__ out, int N) {
    int v = blockIdx.x * 4 + (threadIdx.x >> 6);
    if (v >= N) return;
    const int l = threadIdx.x & 63;
    const int beg = off[v], end = off[v + 1];
    const int cnt = end - beg;
    const float adv = a_d[v];

    float mx = lrelu(a_s[v] + adv);
    for (int idx = beg + l; idx < end; idx += 64)
        mx = fmaxf(mx, lrelu(a_s[ssrc[idx]] + adv));
#pragma unroll
    for (int msk = 1; msk < 64; msk <<= 1) mx = fmaxf(mx, __shfl_xor(mx, msk));
    const float m = mx;

    const int eq = l >> 4, cq = l & 15, c0 = cq * 4;
    float s_;
    float ac[4];
    {
        us4 xv = *(const us4*)(xs + (size_t)v * 64 + c0);
        float pv = (eq == 0) ? __expf(lrelu(a_s[v] + adv) - m) : 0.f;
        s_ = pv;
#pragma unroll
        for (int i = 0; i < 4; i++) ac[i] = pv * bf2f(xv[i]);
    }

#define AG2_LOAD(S, POS) { int pp = min((POS) + eq, cl); int uu = ssrc[beg + pp]; \
        aa##S = a_s[uu]; x##S = *(const us4*)(xs + (size_t)uu * 64 + c0); }
#define AG2_PROC(S) { float p = __expf(lrelu(aa##S + adv) - m); s_ += p; \
        _Pragma("unroll") for (int i = 0; i < 4; i++) ac[i] += p * bf2f(x##S[i]); }

    float aa0 = 0.f, aa1 = 0.f;
    us4 x0 = {0}, x1 = {0};
    int k = 0;
    if (cnt > 0) {
        const int cl = cnt - 1;
        AG2_LOAD(0, 0) AG2_LOAD(1, 4)
        for (; k + 8 <= cnt; k += 8) {
            AG2_PROC(0) AG2_LOAD(0, k + 8)
            AG2_PROC(1) AG2_LOAD(1, k + 12)
        }
        if (k + eq < cnt)     AG2_PROC(0)
        if (k + 4 + eq < cnt) AG2_PROC(1)
    }
#undef AG2_LOAD
#undef AG2_PROC

#pragma unroll
    for (int msk = 16; msk < 64; msk <<= 1) {
        s_ += __shfl_xor(s_, msk);
#pragma unroll
        for (int i = 0; i < 4; i++) ac[i] += __shfl_xor(ac[i], msk);
    }
    if (eq == 0) {
        float inv = __builtin_amdgcn_rcpf(s_ + 1e-16f);
        float4 b4 = *(const float4*)(bias + c0);
        float4 o;
        o.x = fmaxf(ac[0] * inv + b4.x, 0.f);
        o.y = fmaxf(ac[1] * inv + b4.y, 0.f);
        o.z = fmaxf(ac[2] * inv + b4.z, 0.f);
        o.w = fmaxf(ac[3] * inv + b4.w, 0.f);
        *(float4*)(out + (size_t)v * 64 + c0) = o;
    }
}

// --------------------------- pooling + FC ----------------------------------
__global__ void k_pool(const float* __restrict__ h3, const int* __restrict__ batch,
                       const float* __restrict__ fc_w, const float* __restrict__ fc_b,
                       float* __restrict__ out, int N, int G) {
    __shared__ float red[4][64];
    __shared__ float meanv[64];
    __shared__ float lg[10];
    int g = blockIdx.x;
    int tid = threadIdx.x, c = tid & 63, ro = tid >> 6;
    // inline binary-search bounds (all threads redundantly)
    int lo = 0, hi = N;
    while (lo < hi) { int mid = (lo + hi) >> 1; if (batch[mid] < g) lo = mid + 1; else hi = mid; }
    int s0 = lo;
    lo = 0; hi = N;
    while (lo < hi) { int mid = (lo + hi) >> 1; if (batch[mid] < g + 1) lo = mid + 1; else hi = mid; }
    int s1 = lo;
    float p = 0.f;
    for (int r = s0 + ro; r < s1; r += 4) p += h3[(size_t)r * 64 + c];
    red[ro][c] = p;
    __syncthreads();
    if (tid < 64) {
        float tot = red[0][c] + red[1][c] + red[2][c] + red[3][c];
        float cnt = (float)max(s1 - s0, 1);
        meanv[c] = tot / cnt;
    }
    __syncthreads();
    if (tid < 10) {
        float lv = fc_b[tid];
        for (int k = 0; k < 64; k++) lv += meanv[k] * fc_w[k * 10 + tid];
        lg[tid] = lv;
    }
    __syncthreads();
    if (tid == 0) {
        float mxv = lg[0];
        for (int k = 1; k < 10; k++) mxv = fmaxf(mxv, lg[k]);
        float ss = 0.f;
        for (int k = 0; k < 10; k++) ss += expf(lg[k] - mxv);
        float lse = mxv + logf(ss);
        for (int k = 0; k < 10; k++) out[g * 10 + k] = lg[k] - lse;
    }
}

// ---------------------------------------------------------------------------
extern "C" void kernel_launch(void* const* d_in, const int* in_sizes, int n_in,
                              void* d_out, int out_size, void* d_ws, size_t ws_size,
                              hipStream_t stream) {
    const float* x = (const float*)d_in[0];
    const int* ei = (const int*)d_in[1];
    const int* batch = (const int*)d_in[2];
    const float* w_ih = (const float*)d_in[4];
    const float* w_hh = (const float*)d_in[5];
    const float* b_ih = (const float*)d_in[6];
    const float* b_hh = (const float*)d_in[7];
    const float* W1 = (const float*)d_in[8];
    const float* as1 = (const float*)d_in[9];
    const float* ad1 = (const float*)d_in[10];
    const float* b1 = (const float*)d_in[11];
    const float* W2 = (const float*)d_in[12];
    const float* as2 = (const float*)d_in[13];
    const float* ad2 = (const float*)d_in[14];
    const float* b2 = (const float*)d_in[15];
    const float* fc_w = (const float*)d_in[18];
    const float* fc_b = (const float*)d_in[19];
    float* out = (float*)d_out;

    const int N = in_sizes[0] / (8 * 128);   // 100000
    const int E = in_sizes[1] / 2;           // 1600000
    const int G = 128;

    char* ws = (char*)d_ws;
    size_t cur = 0;
    auto alloc = [&](size_t b) { size_t r = cur; cur += (b + 255) & ~(size_t)255; return r; };
    unsigned short* p_gi = (unsigned short*)(ws + alloc((size_t)12 * 4 * 64 * 8 * 2));
    unsigned short* p_gh = (unsigned short*)(ws + alloc((size_t)12 * 2 * 64 * 8 * 2));
    unsigned short* p_w1 = (unsigned short*)(ws + alloc((size_t)16 * 2 * 64 * 8 * 2));
    unsigned short* p_w2 = (unsigned short*)(ws + alloc((size_t)4 * 8 * 64 * 8 * 2));
    unsigned short* p_v1 = (unsigned short*)(ws + alloc((size_t)2 * 64 * 8 * 2));
    unsigned short* p_v2 = (unsigned short*)(ws + alloc((size_t)8 * 64 * 8 * 2));
    unsigned short* h1 = (unsigned short*)(ws + alloc((size_t)N * 64 * 2));
    unsigned short* xs1 = (unsigned short*)(ws + alloc((size_t)N * 256 * 2));  // reused as xs2
    unsigned short* h2 = (unsigned short*)(ws + alloc((size_t)N * 256 * 2));
    float* h3 = (float*)(ws + alloc((size_t)N * 64 * 4));
    float* aS = (float*)(ws + alloc((size_t)N * 4 * 4));
    float* aD = (float*)(ws + alloc((size_t)N * 4 * 4));
    int* deg = (int*)(ws + alloc((size_t)N * 4));       // reused as cursor
    int* offp = (int*)(ws + alloc((size_t)(N + 1) * 4));
    int* inc = (int*)(ws + alloc((size_t)N * 4));
    int* bsum = (int*)(ws + alloc((size_t)128 * 4));
    int* ssrc = (int*)(ws + alloc((size_t)E * 4));

    // ---- weight prep (single dispatcher) ----
    k_prep<<<37, 256, 0, stream>>>(w_ih, w_hh, W1, W2, as1, ad1, as2, ad2,
                                   p_gi, p_gh, p_w1, p_w2, p_v1, p_v2);

    // ---- CSR by dst ----
    const int nbscan = (N + 1023) / 1024;  // 98
    hipMemsetAsync(deg, 0, (size_t)N * 4, stream);
    k_deg<<<(E + 255) / 256, 256, 0, stream>>>(ei + E, deg, E);
    k_scan1<<<nbscan, 1024, 0, stream>>>(deg, inc, bsum, N);
    k_scan2<<<1, 128, 0, stream>>>(bsum, nbscan);
    k_scan3<<<(N + 255) / 256, 256, 0, stream>>>(inc, bsum, offp, N);
    hipMemsetAsync(deg, 0, (size_t)N * 4, stream);  // reuse as cursor
    k_fill<<<(E + 255) / 256, 256, 0, stream>>>(ei, ei + E, offp, deg, ssrc, E);

    const int nb64 = (N + 63) / 64;
    const int nb4 = (N + 3) / 4;

    // ---- GRU ----
    k_gru<<<nb64, 256, 0, stream>>>(x, p_gi, p_gh, b_ih, b_hh, h1, N);

    // ---- GAT layer 1 ----
    k_gemm1<<<nb64, 256, 0, stream>>>(h1, p_w1, p_v1, xs1, aS, aD, N);
    k_agg1<<<nb4, 256, 0, stream>>>(xs1, aS, aD, offp, ssrc, b1, h2, N);

    // ---- GAT layer 2 ----
    k_gemm2<<<nb64, 256, 0, stream>>>(h2, p_w2, p_v2, xs1 /*xs2*/, aS, aD, N);
    k_agg2<<<nb4, 256, 0, stream>>>(xs1, aS, aD, offp, ssrc, b2, h3, N);

    // ---- pooling + FC + log_softmax (aw == 1 exactly; attn_w/b unused) ----
    k_pool<<<G, 256, 0, stream>>>(h3, batch, fc_w, fc_b, out, N, G);
}

// Round 4
// 481.066 us; speedup vs baseline: 2.2162x; 1.1885x over previous
//
#include <hip/hip_runtime.h>
#include <stdint.h>

// ---------------------------------------------------------------------------
// DAGNN: GRU(128->64, T=8) -> GATConv(64->4x64, concat) -> GATConv(256->64)
//        -> segment-mean pool -> FC(64->10) -> log_softmax
// R4: fp8(e4m3) gather tables for GAT aggregation (halves gather bytes),
// max-pass removed (logits bounded -> exp directly), wider edge-parallel
// gathers (4 edges/wave-iter L1, 8 edges/wave-iter L2), permuted fp8 layout
// for packed GEMM1 epilogue stores.
// ---------------------------------------------------------------------------

typedef __attribute__((ext_vector_type(8))) short short8;
typedef __attribute__((ext_vector_type(4))) float f32x4;
typedef __attribute__((ext_vector_type(2))) float f32x2;
typedef __attribute__((ext_vector_type(2))) unsigned int u32x2;
typedef __attribute__((ext_vector_type(4))) unsigned int u32x4;

__device__ __forceinline__ unsigned short f2bf(float f) {   // RNE (cold paths)
    unsigned u = __float_as_uint(f);
    u += 0x7FFFu + ((u >> 16) & 1u);
    return (unsigned short)(u >> 16);
}
__device__ __forceinline__ float bf2f(unsigned short h) {
    return __uint_as_float(((unsigned)h) << 16);
}
__device__ __forceinline__ unsigned cvtpk(float lo, float hi) {  // 2xf32->2xbf16
    unsigned r;
    asm("v_cvt_pk_bf16_f32 %0, %1, %2" : "=v"(r) : "v"(lo), "v"(hi));
    return r;
}
__device__ __forceinline__ unsigned short f2bfq(float v) {
    unsigned r;
    asm("v_cvt_pk_bf16_f32 %0, %1, %1" : "=v"(r) : "v"(v));
    return (unsigned short)r;
}
__device__ __forceinline__ float lrelu(float x) { return x > 0.f ? x : 0.2f * x; }
__device__ __forceinline__ float fsig(float a) {
    return __builtin_amdgcn_rcpf(1.f + __expf(-a));
}
__device__ __forceinline__ float ftanh(float a) {
    return 2.f * __builtin_amdgcn_rcpf(1.f + __expf(-2.f * a)) - 1.f;
}
// fp8 e4m3 (OCP) pack/unpack
__device__ __forceinline__ unsigned enc4fp8(float a, float b, float c, float d) {
    unsigned r = __builtin_amdgcn_cvt_pk_fp8_f32(a, b, 0, false);
    r = __builtin_amdgcn_cvt_pk_fp8_f32(c, d, r, true);
    return r;
}
__device__ __forceinline__ unsigned char enc1fp8(float v) {
    return (unsigned char)(__builtin_amdgcn_cvt_pk_fp8_f32(v, v, 0, false) & 0xff);
}

// ---------------------------------------------------------------------------
// Weight prep dispatcher.
// B-frag layout: frag f = ct*KT + kt; elem [f][lane][i] = B[k][col],
//   col = ct*16 + (lane&15), k = kt*32 + (lane>>4)*8 + i
// ---------------------------------------------------------------------------
__device__ void pack_body(const float* __restrict__ src, unsigned short* __restrict__ dst,
                          int K, int NCOL, int ldsrc, int transposed, int blk, int tid) {
    int id = blk * 256 + tid;
    int KT = K >> 5;
    int nfrag = (NCOL >> 4) * KT;
    if (id >= nfrag * 64) return;
    int l = id & 63;
    int f = id >> 6;
    int kt = f % KT, ct = f / KT;
    int col = ct * 16 + (l & 15);
    int kbase = kt * 32 + ((l >> 4) << 3);
#pragma unroll
    for (int i = 0; i < 8; i++) {
        int k = kbase + i;
        float v = transposed ? src[(size_t)col * ldsrc + k] : src[(size_t)k * ldsrc + col];
        dst[((size_t)f * 64 + l) * 8 + i] = f2bf(v);
    }
}
__device__ void packv_body(const float* __restrict__ W, const float* __restrict__ avs,
                           const float* __restrict__ avd, unsigned short* __restrict__ dst,
                           int K, int H, int ldW, int blk, int tid) {
    int id = blk * 256 + tid;
    int KT = K >> 5;
    if (id >= KT * 64) return;
    int l = id & 63, f = id >> 6;
    int col = l & 15;
    int kbase = f * 32 + ((l >> 4) << 3);
    for (int i = 0; i < 8; i++) {
        int k = kbase + i;
        float val = 0.f;
        if (col < 2 * H) {
            int h = col >> 1;
            const float* av = (col & 1) ? avd : avs;
            for (int c = 0; c < 64; c++) val += W[(size_t)k * ldW + h * 64 + c] * av[h * 64 + c];
        }
        dst[((size_t)f * 64 + l) * 8 + i] = f2bf(val);
    }
}
__global__ void k_prep(const float* w_ih, const float* w_hh, const float* W1, const float* W2,
                       const float* as1, const float* ad1, const float* as2, const float* ad2,
                       const float* b1,
                       unsigned short* p_gi, unsigned short* p_gh,
                       unsigned short* p_w1, unsigned short* p_w2,
                       unsigned short* p_v1, unsigned short* p_v2,
                       float* b1p) {
    int b = blockIdx.x, tid = threadIdx.x;
    if (b < 12)      pack_body(w_ih, p_gi, 128, 192, 128, 1, b, tid);
    else if (b < 18) pack_body(w_hh, p_gh, 64, 192, 64, 1, b - 12, tid);
    else if (b < 26) pack_body(W1, p_w1, 64, 256, 256, 0, b - 18, tid);
    else if (b < 34) pack_body(W2, p_w2, 256, 64, 64, 0, b - 26, tid);
    else if (b < 35) packv_body(W1, as1, ad1, p_v1, 64, 4, 256, b - 34, tid);
    else if (b < 37) packv_body(W2, as2, ad2, p_v2, 256, 1, 64, b - 35, tid);
    else {
        // permuted bias: p = (o&0xC0) | ((o&15)<<2) | ((o>>4)&3)
        int o = tid;
        int p = (o & 0xC0) | ((o & 15) << 2) | ((o >> 4) & 3);
        b1p[p] = b1[o];
    }
}

// ---------------------------------------------------------------------------
// Fused GRU (unchanged from R3).
// ---------------------------------------------------------------------------
__launch_bounds__(256, 2)
__global__ void k_gru(const float* __restrict__ x,
                      const unsigned short* __restrict__ pgi,
                      const unsigned short* __restrict__ pgh,
                      const float* __restrict__ b_ih, const float* __restrict__ b_hh,
                      unsigned short* __restrict__ h1, int N) {
    __shared__ unsigned short x_pack[4 * 4 * 64 * 8];
    __shared__ unsigned short h_pack[4 * 2 * 64 * 8];

    const int tid = threadIdx.x;
    const int w = tid >> 6;
    const int l = tid & 63;
    const int row0 = blockIdx.x * 64;

    short8 wgi[3][4], wgh[3][2];
#pragma unroll
    for (int g = 0; g < 3; g++) {
        int ctg = g * 4 + w;
#pragma unroll
        for (int kt = 0; kt < 4; kt++)
            wgi[g][kt] = *(const short8*)(pgi + ((size_t)(ctg * 4 + kt) * 64 + l) * 8);
#pragma unroll
        for (int kt = 0; kt < 2; kt++)
            wgh[g][kt] = *(const short8*)(pgh + ((size_t)(ctg * 2 + kt) * 64 + l) * 8);
    }
    const int j = (w << 4) + (l & 15);
    const float bs_r = b_ih[j] + b_hh[j];
    const float bs_z = b_ih[64 + j] + b_hh[64 + j];
    const float bi_n = b_ih[128 + j], bh_n = b_hh[128 + j];

    f32x4 hreg[4];
    const f32x4 z4 = {0.f, 0.f, 0.f, 0.f};
#pragma unroll
    for (int m = 0; m < 4; m++) hreg[m] = z4;

    const int sr = tid >> 2, sub = tid & 3;
    const int snode = min(row0 + sr, N - 1);
    const int slane = (sr & 15) | (sub << 4);
    const int sm = sr >> 4;
    const float* xbase = x + (size_t)snode * 1024;

    float4 pre[8];
#pragma unroll
    for (int it = 0; it < 4; it++) {
        int d0 = it * 32 + sub * 8;
        pre[2 * it] = *(const float4*)(xbase + d0);
        pre[2 * it + 1] = *(const float4*)(xbase + d0 + 4);
    }

    for (int t = 0; t < 8; t++) {
        u32x4 pk[4];
#pragma unroll
        for (int it = 0; it < 4; it++) {
            float4 va = pre[2 * it], vb = pre[2 * it + 1];
            u32x4 p;
            p[0] = cvtpk(va.x, va.y); p[1] = cvtpk(va.z, va.w);
            p[2] = cvtpk(vb.x, vb.y); p[3] = cvtpk(vb.z, vb.w);
            pk[it] = p;
        }
        if (t > 0) {
#pragma unroll
            for (int m = 0; m < 4; m++)
#pragma unroll
                for (int q = 0; q < 4; q++) {
                    int rl = ((l >> 4) << 2) + q;
                    int lane2 = rl | (((j >> 3) & 3) << 4);
                    h_pack[((m * 2 + (j >> 5)) * 64 + lane2) * 8 + (j & 7)] = f2bfq(hreg[m][q]);
                }
        }
#pragma unroll
        for (int it = 0; it < 4; it++)
            *(u32x4*)&x_pack[((sm * 4 + it) * 64 + slane) * 8] = pk[it];
        __syncthreads();

        if (t < 7) {
            const float* xp = xbase + (t + 1) * 128;
#pragma unroll
            for (int it = 0; it < 4; it++) {
                int d0 = it * 32 + sub * 8;
                pre[2 * it] = *(const float4*)(xp + d0);
                pre[2 * it + 1] = *(const float4*)(xp + d0 + 4);
            }
        }

        f32x4 agi[4][3], aghn[4];
#pragma unroll
        for (int m = 0; m < 4; m++) {
            agi[m][0] = z4; agi[m][1] = z4; agi[m][2] = z4; aghn[m] = z4;
        }

#pragma unroll
        for (int m = 0; m < 4; m++) {
#pragma unroll
            for (int kt = 0; kt < 4; kt++) {
                short8 a = *(const short8*)&x_pack[((m * 4 + kt) * 64 + l) * 8];
#pragma unroll
                for (int g = 0; g < 3; g++)
                    agi[m][g] = __builtin_amdgcn_mfma_f32_16x16x32_bf16(a, wgi[g][kt], agi[m][g], 0, 0, 0);
            }
            if (t > 0) {
#pragma unroll
                for (int kt = 0; kt < 2; kt++) {
                    short8 a = *(const short8*)&h_pack[((m * 2 + kt) * 64 + l) * 8];
                    agi[m][0] = __builtin_amdgcn_mfma_f32_16x16x32_bf16(a, wgh[0][kt], agi[m][0], 0, 0, 0);
                    agi[m][1] = __builtin_amdgcn_mfma_f32_16x16x32_bf16(a, wgh[1][kt], agi[m][1], 0, 0, 0);
                    aghn[m]   = __builtin_amdgcn_mfma_f32_16x16x32_bf16(a, wgh[2][kt], aghn[m], 0, 0, 0);
                }
            }
        }
#pragma unroll
        for (int m = 0; m < 4; m++) {
#pragma unroll
            for (int q = 0; q < 4; q++) {
                float rr = fsig(agi[m][0][q] + bs_r);
                float zz = fsig(agi[m][1][q] + bs_z);
                float hn = aghn[m][q] + bh_n;
                float nn = ftanh(agi[m][2][q] + bi_n + rr * hn);
                hreg[m][q] = nn + zz * (hreg[m][q] - nn);
            }
        }
        __syncthreads();
    }
#pragma unroll
    for (int m = 0; m < 4; m++)
#pragma unroll
        for (int q = 0; q < 4; q++) {
            int node = row0 + (m << 4) + ((l >> 4) << 2) + q;
            if (node < N) h1[(size_t)node * 64 + j] = f2bfq(hreg[m][q]);
        }
}

// ---------------------------------------------------------------------------
// GEMM1: xs1f[N][256] (fp8, permuted p = head*64 + lc*4 + ci) = h1 x W1;
// logits via extra MFMA columns.
// ---------------------------------------------------------------------------
__launch_bounds__(256, 2)
__global__ void k_gemm1(const unsigned short* __restrict__ A,
                        const unsigned short* __restrict__ packB,
                        const unsigned short* __restrict__ pv1,
                        unsigned char* __restrict__ Cf,
                        float* __restrict__ aS, float* __restrict__ aD, int N) {
    constexpr int KT = 2, CPW = 4;
    __shared__ unsigned short a_pack[4 * KT * 64 * 8];

    const int tid = threadIdx.x, w = tid >> 6, l = tid & 63;
    const int row0 = blockIdx.x * 64;

    short8 bf[CPW][KT];
#pragma unroll
    for (int ci = 0; ci < CPW; ci++)
#pragma unroll
        for (int kt = 0; kt < KT; kt++)
            bf[ci][kt] = *(const short8*)(packB + ((size_t)((w * CPW + ci) * KT + kt) * 64 + l) * 8);

    const int sr = tid >> 2, sub = tid & 3;
    const int snode = min(row0 + sr, N - 1);
    const unsigned short* ap = A + (size_t)snode * 64;
#pragma unroll
    for (int it = 0; it < KT; it++) {
        int d0 = it * 32 + sub * 8;
        short8 v = *(const short8*)(ap + d0);
        *(short8*)&a_pack[(((sr >> 4) * KT + it) * 64 + ((sr & 15) | (sub << 4))) * 8] = v;
    }
    __syncthreads();

    const f32x4 z4 = {0.f, 0.f, 0.f, 0.f};
    f32x4 acc[4][CPW];
#pragma unroll
    for (int m = 0; m < 4; m++)
#pragma unroll
        for (int ci = 0; ci < CPW; ci++) acc[m][ci] = z4;

#pragma unroll
    for (int m = 0; m < 4; m++)
#pragma unroll
        for (int kt = 0; kt < KT; kt++) {
            short8 a = *(const short8*)&a_pack[((m * KT + kt) * 64 + l) * 8];
#pragma unroll
            for (int ci = 0; ci < CPW; ci++)
                acc[m][ci] = __builtin_amdgcn_mfma_f32_16x16x32_bf16(a, bf[ci][kt], acc[m][ci], 0, 0, 0);
        }

    f32x4 acce = z4;
#pragma unroll
    for (int kt = 0; kt < KT; kt++) {
        short8 be = *(const short8*)(pv1 + ((size_t)kt * 64 + l) * 8);
        short8 a = *(const short8*)&a_pack[((w * KT + kt) * 64 + l) * 8];
        acce = __builtin_amdgcn_mfma_f32_16x16x32_bf16(a, be, acce, 0, 0, 0);
    }
    int colE = l & 15;
    if (colE < 8) {
        int h = colE >> 1;
#pragma unroll
        for (int q = 0; q < 4; q++) {
            int node = row0 + (w << 4) + ((l >> 4) << 2) + q;
            if (node < N) {
                if (colE & 1) aD[node * 4 + h] = acce[q];
                else          aS[node * 4 + h] = acce[q];
            }
        }
    }

    // fp8 permuted store: dword = bytes{ci=0..3} at node*256 + w*64 + lc*4
    const int lc = l & 15;
#pragma unroll
    for (int m = 0; m < 4; m++)
#pragma unroll
        for (int q = 0; q < 4; q++) {
            int node = row0 + (m << 4) + ((l >> 4) << 2) + q;
            if (node < N) {
                unsigned d = enc4fp8(acc[m][0][q], acc[m][1][q], acc[m][2][q], acc[m][3][q]);
                *(unsigned*)(Cf + (size_t)node * 256 + w * 64 + lc * 4) = d;
            }
        }
}

// ---------------------------------------------------------------------------
// GEMM2: xs2f[N][64] (fp8, standard layout) = h2 x W2; logits via extra cols.
// ---------------------------------------------------------------------------
__launch_bounds__(256, 2)
__global__ void k_gemm2(const unsigned short* __restrict__ A,
                        const unsigned short* __restrict__ packB,
                        const unsigned short* __restrict__ pv2,
                        unsigned char* __restrict__ Cf,
                        float* __restrict__ aS, float* __restrict__ aD, int N) {
    constexpr int KT = 8;
    __shared__ unsigned short a_pack[4 * KT * 64 * 8];

    const int tid = threadIdx.x, w = tid >> 6, l = tid & 63;
    const int row0 = blockIdx.x * 64;

    short8 bf[KT];
#pragma unroll
    for (int kt = 0; kt < KT; kt++)
        bf[kt] = *(const short8*)(packB + ((size_t)(w * KT + kt) * 64 + l) * 8);

    const int sr = tid >> 2, sub = tid & 3;
    const int snode = min(row0 + sr, N - 1);
    const unsigned short* ap = A + (size_t)snode * 256;
#pragma unroll
    for (int it = 0; it < KT; it++) {
        int d0 = it * 32 + sub * 8;
        short8 v = *(const short8*)(ap + d0);
        *(short8*)&a_pack[(((sr >> 4) * KT + it) * 64 + ((sr & 15) | (sub << 4))) * 8] = v;
    }
    __syncthreads();

    const f32x4 z4 = {0.f, 0.f, 0.f, 0.f};
    f32x4 acc[4];
#pragma unroll
    for (int m = 0; m < 4; m++) acc[m] = z4;

#pragma unroll
    for (int m = 0; m < 4; m++)
#pragma unroll
        for (int kt = 0; kt < KT; kt++) {
            short8 a = *(const short8*)&a_pack[((m * KT + kt) * 64 + l) * 8];
            acc[m] = __builtin_amdgcn_mfma_f32_16x16x32_bf16(a, bf[kt], acc[m], 0, 0, 0);
        }

    f32x4 acce = z4;
#pragma unroll
    for (int kt = 0; kt < KT; kt++) {
        short8 be = *(const short8*)(pv2 + ((size_t)kt * 64 + l) * 8);
        short8 a = *(const short8*)&a_pack[((w * KT + kt) * 64 + l) * 8];
        acce = __builtin_amdgcn_mfma_f32_16x16x32_bf16(a, be, acce, 0, 0, 0);
    }
    int colE = l & 15;
    if (colE < 2) {
#pragma unroll
        for (int q = 0; q < 4; q++) {
            int node = row0 + (w << 4) + ((l >> 4) << 2) + q;
            if (node < N) {
                if (colE) aD[node] = acce[q];
                else      aS[node] = acce[q];
            }
        }
    }

    int colw = w * 16 + (l & 15);
#pragma unroll
    for (int m = 0; m < 4; m++)
#pragma unroll
        for (int q = 0; q < 4; q++) {
            int node = row0 + (m << 4) + ((l >> 4) << 2) + q;
            if (node < N) Cf[(size_t)node * 64 + colw] = enc1fp8(acc[m][q]);
        }
}

// --------------------------- CSR build -------------------------------------
__global__ void k_deg(const int* __restrict__ dst, int* __restrict__ deg, int E) {
    int i = blockIdx.x * blockDim.x + threadIdx.x;
    if (i < E) atomicAdd(&deg[dst[i]], 1);
}
__global__ void k_scan1(const int* __restrict__ deg, int* __restrict__ inc,
                        int* __restrict__ bsum, int N) {
    __shared__ int wsum[16];
    int tid = threadIdx.x;
    int i = blockIdx.x * 1024 + tid;
    int v = (i < N) ? deg[i] : 0;
    int lane = tid & 63, wv = tid >> 6;
    int s = v;
#pragma unroll
    for (int d = 1; d < 64; d <<= 1) {
        int t = __shfl_up(s, d);
        if (lane >= d) s += t;
    }
    if (lane == 63) wsum[wv] = s;
    __syncthreads();
    if (tid == 0) {
        int run = 0;
#pragma unroll
        for (int k = 0; k < 16; k++) { int t = wsum[k]; wsum[k] = run; run += t; }
        bsum[blockIdx.x] = run;
    }
    __syncthreads();
    s += wsum[wv];
    if (i < N) inc[i] = s;
}
__global__ void k_scan2(int* __restrict__ bsum, int nb) {
    __shared__ int w0tot;
    int tid = threadIdx.x;
    int v = (tid < nb) ? bsum[tid] : 0;
    int lane = tid & 63, wv = tid >> 6;
    int s = v;
#pragma unroll
    for (int d = 1; d < 64; d <<= 1) {
        int t = __shfl_up(s, d);
        if (lane >= d) s += t;
    }
    if (tid == 63) w0tot = s;
    __syncthreads();
    int ex = s - v + (wv ? w0tot : 0);
    if (tid < nb) bsum[tid] = ex;
}
__global__ void k_scan3(const int* __restrict__ inc, const int* __restrict__ bsum,
                        int* __restrict__ off, int* __restrict__ cursor, int N) {
    int i = blockIdx.x * blockDim.x + threadIdx.x;
    if (i < N) { off[i + 1] = inc[i] + bsum[i >> 10]; cursor[i] = 0; }
    if (i == 0) off[0] = 0;
}
__global__ void k_fill(const int* __restrict__ srcv, const int* __restrict__ dstv,
                       const int* __restrict__ off, int* __restrict__ cursor,
                       int* __restrict__ ssrc, int E) {
    int i = blockIdx.x * blockDim.x + threadIdx.x;
    if (i < E) {
        int d = dstv[i];
        int pos = off[d] + atomicAdd(&cursor[d], 1);
        ssrc[pos] = srcv[i];
    }
}

// ---------------------------------------------------------------------------
// GAT layer-1 aggregation, fp8 gather, no max pass.
// Wave per dst node; 4 edges/iter (quarter-wave x 16B), 3 slots.
// xs layout: permuted p = head*64 + lc*4 + ci (lane cq reads bytes cq*16..+15)
// ---------------------------------------------------------------------------
__global__ void k_agg1(const unsigned char* __restrict__ xs,
                       const float* __restrict__ a_s, const float* __restrict__ a_d,
                       const int* __restrict__ off, const int* __restrict__ ssrc,
                       const float* __restrict__ b1p,
                       unsigned short* __restrict__ out, int N) {
    int v = blockIdx.x * 4 + (threadIdx.x >> 6);
    if (v >= N) return;
    const int l = threadIdx.x & 63;
    const int eq = l >> 4;       // edge slot within quad
    const int cq = l & 15;       // 16-byte chunk
    const int H = cq >> 2;       // head
    const float adv = a_d[v * 4 + H];
    const int beg = off[v], end = off[v + 1];
    const int cnt = end - beg;

    float s_;
    float ac[16];
    {
        u32x4 xv = *(const u32x4*)(xs + (size_t)v * 256 + cq * 16);
        float pv = (eq == 0) ? __expf(lrelu(a_s[v * 4 + H] + adv)) : 0.f;
        s_ = pv;
#pragma unroll
        for (int wd = 0; wd < 4; wd++) {
            f32x2 lo = __builtin_amdgcn_cvt_pk_f32_fp8(xv[wd], false);
            f32x2 hi = __builtin_amdgcn_cvt_pk_f32_fp8(xv[wd], true);
            ac[wd * 4 + 0] = pv * lo[0]; ac[wd * 4 + 1] = pv * lo[1];
            ac[wd * 4 + 2] = pv * hi[0]; ac[wd * 4 + 3] = pv * hi[1];
        }
    }

#define AG1_LOAD(S, POS) { int pp = min((POS) + eq, cl); int uu = ssrc[beg + pp]; \
        aa##S = a_s[uu * 4 + H]; x##S = *(const u32x4*)(xs + (size_t)uu * 256 + cq * 16); }
#define AG1_PROC(S) { float p = __expf(lrelu(aa##S + adv)); s_ += p; \
        _Pragma("unroll") for (int wd = 0; wd < 4; wd++) { \
            f32x2 lo = __builtin_amdgcn_cvt_pk_f32_fp8(x##S[wd], false); \
            f32x2 hi = __builtin_amdgcn_cvt_pk_f32_fp8(x##S[wd], true); \
            ac[wd * 4 + 0] += p * lo[0]; ac[wd * 4 + 1] += p * lo[1]; \
            ac[wd * 4 + 2] += p * hi[0]; ac[wd * 4 + 3] += p * hi[1]; } }

    float aa0 = 0.f, aa1 = 0.f, aa2 = 0.f;
    u32x4 x0 = {0, 0, 0, 0}, x1 = {0, 0, 0, 0}, x2 = {0, 0, 0, 0};
    int k = 0;
    if (cnt > 0) {
        const int cl = cnt - 1;
        AG1_LOAD(0, 0) AG1_LOAD(1, 4) AG1_LOAD(2, 8)
        for (; k + 12 <= cnt; k += 12) {
            AG1_PROC(0) AG1_LOAD(0, k + 12)
            AG1_PROC(1) AG1_LOAD(1, k + 16)
            AG1_PROC(2) AG1_LOAD(2, k + 20)
        }
        if (k + eq < cnt)     AG1_PROC(0)
        if (k + 4 + eq < cnt) AG1_PROC(1)
        if (k + 8 + eq < cnt) AG1_PROC(2)
    }
#undef AG1_LOAD
#undef AG1_PROC

#pragma unroll
    for (int msk = 16; msk < 64; msk <<= 1) {
        s_ += __shfl_xor(s_, msk);
#pragma unroll
        for (int i = 0; i < 16; i++) ac[i] += __shfl_xor(ac[i], msk);
    }

    if (eq == 0) {
        float inv = __builtin_amdgcn_rcpf(s_ + 1e-16f);
        float bp[16];
#pragma unroll
        for (int i = 0; i < 4; i++)
            *(float4*)&bp[i * 4] = *(const float4*)(b1p + cq * 16 + i * 4);
        // un-permute: ac[jj] (jj = t*4+b) -> orig channel H*64 + b*16 + (cq&3)*4 + t
#pragma unroll
        for (int b = 0; b < 4; b++) {
            float r0 = fmaxf(ac[b]      * inv + bp[b],      0.f);
            float r1 = fmaxf(ac[4 + b]  * inv + bp[4 + b],  0.f);
            float r2 = fmaxf(ac[8 + b]  * inv + bp[8 + b],  0.f);
            float r3 = fmaxf(ac[12 + b] * inv + bp[12 + b], 0.f);
            u32x2 o;
            o[0] = cvtpk(r0, r1); o[1] = cvtpk(r2, r3);
            *(u32x2*)(out + (size_t)v * 256 + H * 64 + b * 16 + (cq & 3) * 4) = o;
        }
    }
}

// ---------------------------------------------------------------------------
// GAT layer-2 aggregation, fp8 gather, no max pass.
// Wave per node; 8 edges/iter (8 lanes x 8B each), 2 slots.
// ---------------------------------------------------------------------------
__global__ void k_agg2(const unsigned char* __restrict__ xs,
                       const float* __restrict__ a_s, const float* __restrict__ a_d,
                       const int* __restrict__ off, const int* __restrict__ ssrc,
                       const float* __restrict__ bias,
                       float* __restrict__ out, int N) {
    int v = blockIdx.x * 4 + (threadIdx.x >> 6);
    if (v >= N) return;
    const int l = threadIdx.x & 63;
    const int eo = l >> 3;       // edge slot within octet (0..7)
    const int cq = l & 7;        // 8-byte chunk
    const int c0 = cq * 8;
    const float adv = a_d[v];
    const int beg = off[v], end = off[v + 1];
    const int cnt = end - beg;

    float s_;
    float ac[8];
    {
        u32x2 xv = *(const u32x2*)(xs + (size_t)v * 64 + c0);
        float pv = (eo == 0) ? __expf(lrelu(a_s[v] + adv)) : 0.f;
        s_ = pv;
#pragma unroll
        for (int wd = 0; wd < 2; wd++) {
            f32x2 lo = __builtin_amdgcn_cvt_pk_f32_fp8(xv[wd], false);
            f32x2 hi = __builtin_amdgcn_cvt_pk_f32_fp8(xv[wd], true);
            ac[wd * 4 + 0] = pv * lo[0]; ac[wd * 4 + 1] = pv * lo[1];
            ac[wd * 4 + 2] = pv * hi[0]; ac[wd * 4 + 3] = pv * hi[1];
        }
    }

#define AG2_LOAD(S, POS) { int pp = min((POS) + eo, cl); int uu = ssrc[beg + pp]; \
        aa##S = a_s[uu]; x##S = *(const u32x2*)(xs + (size_t)uu * 64 + c0); }
#define AG2_PROC(S) { float p = __expf(lrelu(aa##S + adv)); s_ += p; \
        _Pragma("unroll") for (int wd = 0; wd < 2; wd++) { \
            f32x2 lo = __builtin_amdgcn_cvt_pk_f32_fp8(x##S[wd], false); \
            f32x2 hi = __builtin_amdgcn_cvt_pk_f32_fp8(x##S[wd], true); \
            ac[wd * 4 + 0] += p * lo[0]; ac[wd * 4 + 1] += p * lo[1]; \
            ac[wd * 4 + 2] += p * hi[0]; ac[wd * 4 + 3] += p * hi[1]; } }

    float aa0 = 0.f, aa1 = 0.f;
    u32x2 x0 = {0, 0}, x1 = {0, 0};
    int k = 0;
    if (cnt > 0) {
        const int cl = cnt - 1;
        AG2_LOAD(0, 0) AG2_LOAD(1, 8)
        for (; k + 16 <= cnt; k += 16) {
            AG2_PROC(0) AG2_LOAD(0, k + 16)
            AG2_PROC(1) AG2_LOAD(1, k + 24)
        }
        if (k + eo < cnt)     AG2_PROC(0)
        if (k + 8 + eo < cnt) AG2_PROC(1)
    }
#undef AG2_LOAD
#undef AG2_PROC

#pragma unroll
    for (int msk = 8; msk < 64; msk <<= 1) {
        s_ += __shfl_xor(s_, msk);
#pragma unroll
        for (int i = 0; i < 8; i++) ac[i] += __shfl_xor(ac[i], msk);
    }
    if (eo == 0) {
        float inv = __builtin_amdgcn_rcpf(s_ + 1e-16f);
        float4 b4a = *(const float4*)(bias + c0);
        float4 b4b = *(const float4*)(bias + c0 + 4);
        float4 o1, o2;
        o1.x = fmaxf(ac[0] * inv + b4a.x, 0.f);
        o1.y = fmaxf(ac[1] * inv + b4a.y, 0.f);
        o1.z = fmaxf(ac[2] * inv + b4a.z, 0.f);
        o1.w = fmaxf(ac[3] * inv + b4a.w, 0.f);
        o2.x = fmaxf(ac[4] * inv + b4b.x, 0.f);
        o2.y = fmaxf(ac[5] * inv + b4b.y, 0.f);
        o2.z = fmaxf(ac[6] * inv + b4b.z, 0.f);
        o2.w = fmaxf(ac[7] * inv + b4b.w, 0.f);
        *(float4*)(out + (size_t)v * 64 + c0) = o1;
        *(float4*)(out + (size_t)v * 64 + c0 + 4) = o2;
    }
}

// --------------------------- pooling + FC ----------------------------------
__global__ void k_pool(const float* __restrict__ h3, const int* __restrict__ batch,
                       const float* __restrict__ fc_w, const float* __restrict__ fc_b,
                       float* __restrict__ out, int N, int G) {
    __shared__ float red[4][64];
    __shared__ float meanv[64];
    __shared__ float lg[10];
    int g = blockIdx.x;
    int tid = threadIdx.x, c = tid & 63, ro = tid >> 6;
    int lo = 0, hi = N;
    while (lo < hi) { int mid = (lo + hi) >> 1; if (batch[mid] < g) lo = mid + 1; else hi = mid; }
    int s0 = lo;
    lo = 0; hi = N;
    while (lo < hi) { int mid = (lo + hi) >> 1; if (batch[mid] < g + 1) lo = mid + 1; else hi = mid; }
    int s1 = lo;
    float p = 0.f;
    for (int r = s0 + ro; r < s1; r += 4) p += h3[(size_t)r * 64 + c];
    red[ro][c] = p;
    __syncthreads();
    if (tid < 64) {
        float tot = red[0][c] + red[1][c] + red[2][c] + red[3][c];
        float cnt = (float)max(s1 - s0, 1);
        meanv[c] = tot / cnt;
    }
    __syncthreads();
    if (tid < 10) {
        float lv = fc_b[tid];
        for (int k = 0; k < 64; k++) lv += meanv[k] * fc_w[k * 10 + tid];
        lg[tid] = lv;
    }
    __syncthreads();
    if (tid == 0) {
        float mxv = lg[0];
        for (int k = 1; k < 10; k++) mxv = fmaxf(mxv, lg[k]);
        float ss = 0.f;
        for (int k = 0; k < 10; k++) ss += expf(lg[k] - mxv);
        float lse = mxv + logf(ss);
        for (int k = 0; k < 10; k++) out[g * 10 + k] = lg[k] - lse;
    }
}

// ---------------------------------------------------------------------------
extern "C" void kernel_launch(void* const* d_in, const int* in_sizes, int n_in,
                              void* d_out, int out_size, void* d_ws, size_t ws_size,
                              hipStream_t stream) {
    const float* x = (const float*)d_in[0];
    const int* ei = (const int*)d_in[1];
    const int* batch = (const int*)d_in[2];
    const float* w_ih = (const float*)d_in[4];
    const float* w_hh = (const float*)d_in[5];
    const float* b_ih = (const float*)d_in[6];
    const float* b_hh = (const float*)d_in[7];
    const float* W1 = (const float*)d_in[8];
    const float* as1 = (const float*)d_in[9];
    const float* ad1 = (const float*)d_in[10];
    const float* b1 = (const float*)d_in[11];
    const float* W2 = (const float*)d_in[12];
    const float* as2 = (const float*)d_in[13];
    const float* ad2 = (const float*)d_in[14];
    const float* b2 = (const float*)d_in[15];
    const float* fc_w = (const float*)d_in[18];
    const float* fc_b = (const float*)d_in[19];
    float* out = (float*)d_out;

    const int N = in_sizes[0] / (8 * 128);   // 100000
    const int E = in_sizes[1] / 2;           // 1600000
    const int G = 128;

    char* ws = (char*)d_ws;
    size_t cur = 0;
    auto alloc = [&](size_t b) { size_t r = cur; cur += (b + 255) & ~(size_t)255; return r; };
    unsigned short* p_gi = (unsigned short*)(ws + alloc((size_t)12 * 4 * 64 * 8 * 2));
    unsigned short* p_gh = (unsigned short*)(ws + alloc((size_t)12 * 2 * 64 * 8 * 2));
    unsigned short* p_w1 = (unsigned short*)(ws + alloc((size_t)16 * 2 * 64 * 8 * 2));
    unsigned short* p_w2 = (unsigned short*)(ws + alloc((size_t)4 * 8 * 64 * 8 * 2));
    unsigned short* p_v1 = (unsigned short*)(ws + alloc((size_t)2 * 64 * 8 * 2));
    unsigned short* p_v2 = (unsigned short*)(ws + alloc((size_t)8 * 64 * 8 * 2));
    float* b1p = (float*)(ws + alloc((size_t)256 * 4));
    unsigned short* h1 = (unsigned short*)(ws + alloc((size_t)N * 64 * 2));
    unsigned char* xs1f = (unsigned char*)(ws + alloc((size_t)N * 256));  // fp8; reused as xs2f
    unsigned short* h2 = (unsigned short*)(ws + alloc((size_t)N * 256 * 2));
    float* h3 = (float*)(ws + alloc((size_t)N * 64 * 4));
    float* aS = (float*)(ws + alloc((size_t)N * 4 * 4));
    float* aD = (float*)(ws + alloc((size_t)N * 4 * 4));
    int* deg = (int*)(ws + alloc((size_t)N * 4));       // reused as cursor
    int* offp = (int*)(ws + alloc((size_t)(N + 1) * 4));
    int* inc = (int*)(ws + alloc((size_t)N * 4));
    int* bsum = (int*)(ws + alloc((size_t)128 * 4));
    int* ssrc = (int*)(ws + alloc((size_t)E * 4));

    // ---- weight prep ----
    k_prep<<<38, 256, 0, stream>>>(w_ih, w_hh, W1, W2, as1, ad1, as2, ad2, b1,
                                   p_gi, p_gh, p_w1, p_w2, p_v1, p_v2, b1p);

    // ---- CSR by dst ----
    const int nbscan = (N + 1023) / 1024;  // 98
    hipMemsetAsync(deg, 0, (size_t)N * 4, stream);
    k_deg<<<(E + 255) / 256, 256, 0, stream>>>(ei + E, deg, E);
    k_scan1<<<nbscan, 1024, 0, stream>>>(deg, inc, bsum, N);
    k_scan2<<<1, 128, 0, stream>>>(bsum, nbscan);
    k_scan3<<<(N + 255) / 256, 256, 0, stream>>>(inc, bsum, offp, deg /*cursor*/, N);
    k_fill<<<(E + 255) / 256, 256, 0, stream>>>(ei, ei + E, offp, deg, ssrc, E);

    const int nb64 = (N + 63) / 64;
    const int nb4 = (N + 3) / 4;

    // ---- GRU ----
    k_gru<<<nb64, 256, 0, stream>>>(x, p_gi, p_gh, b_ih, b_hh, h1, N);

    // ---- GAT layer 1 ----
    k_gemm1<<<nb64, 256, 0, stream>>>(h1, p_w1, p_v1, xs1f, aS, aD, N);
    k_agg1<<<nb4, 256, 0, stream>>>(xs1f, aS, aD, offp, ssrc, b1p, h2, N);

    // ---- GAT layer 2 ----
    k_gemm2<<<nb64, 256, 0, stream>>>(h2, p_w2, p_v2, xs1f /*xs2f*/, aS, aD, N);
    k_agg2<<<nb4, 256, 0, stream>>>(xs1f, aS, aD, offp, ssrc, b2, h3, N);

    // ---- pooling + FC + log_softmax (aw == 1 exactly; attn_w/b unused) ----
    k_pool<<<G, 256, 0, stream>>>(h3, batch, fc_w, fc_b, out, N, G);
}